// Round 3
// baseline (1267.871 us; speedup 1.0000x reference)
//
#include <hip/hip_runtime.h>
#include <hip/hip_bf16.h>

#define BN_EPS 1e-5f

typedef __attribute__((ext_vector_type(8))) short short8v;
typedef __attribute__((ext_vector_type(4))) float f32x4;
typedef __hip_bfloat16 bf16;

// ---------------------------------------------------------------- CSR build
__global__ void count_kernel(const int* __restrict__ dst, int* __restrict__ deg,
                             int E, int N) {
    int i = blockIdx.x * blockDim.x + threadIdx.x;
    if (i >= E) return;
    int d = dst[i];
    d = min(max(d, 0), N - 1);
    atomicAdd(&deg[d], 1);
}

__global__ __launch_bounds__(1024) void scan_kernel(const int* __restrict__ deg,
                                                    int* __restrict__ off,
                                                    int* __restrict__ cur, int N) {
    __shared__ int wsum[16];
    int t = threadIdx.x;
    int chunk = (N + 1023) / 1024;
    int lo = t * chunk, hi = min(N, lo + chunk);
    int s = 0;
    for (int i = lo; i < hi; ++i) s += deg[i];
    int lane = t & 63, w = t >> 6;
    int v = s;
#pragma unroll
    for (int d = 1; d < 64; d <<= 1) {
        int u = __shfl_up(v, d, 64);
        if (lane >= d) v += u;
    }
    if (lane == 63) wsum[w] = v;
    __syncthreads();
    if (w == 0 && lane < 16) {
        int xx = wsum[lane];
#pragma unroll
        for (int d = 1; d < 16; d <<= 1) {
            int u = __shfl_up(xx, d, 64);
            if (lane >= d) xx += u;
        }
        wsum[lane] = xx;
    }
    __syncthreads();
    int base = (w > 0 ? wsum[w - 1] : 0) + (v - s);  // exclusive prefix
    int run = base;
    for (int i = lo; i < hi; ++i) {
        off[i] = run; cur[i] = run; run += deg[i];
    }
    if (t == 1023) off[N] = run;
}

// also emits CSR-permuted source ids
__global__ void fill_kernel(const int* __restrict__ src, const int* __restrict__ dst,
                            int* __restrict__ cur, int* __restrict__ elist,
                            int* __restrict__ srcs, int E, int N) {
    int i = blockIdx.x * blockDim.x + threadIdx.x;
    if (i >= E) return;
    int d = dst[i];
    d = min(max(d, 0), N - 1);
    int p = atomicAdd(&cur[d], 1);
    elist[p] = i;
    srcs[p] = min(max(src[i], 0), N - 1);
}

// ---------------------------------------------------------- dtype converts
__global__ void conv_bf16_kernel(const float* __restrict__ in, bf16* __restrict__ out,
                                 int n) {
    int i = (blockIdx.x * blockDim.x + threadIdx.x) * 4;
    if (i + 3 < n) {
        float4 v = *(const float4*)&in[i];
        out[i + 0] = __float2bfloat16(v.x);
        out[i + 1] = __float2bfloat16(v.y);
        out[i + 2] = __float2bfloat16(v.z);
        out[i + 3] = __float2bfloat16(v.w);
    } else {
        for (int j = i; j < n && j >= 0; ++j) out[j] = __float2bfloat16(in[j]);
    }
}

// transpose+convert all 6 MLP weights: wt[base + n*K + k] = w[k*N + n]
__global__ void conv_w_kernel(const float* __restrict__ w1a, const float* __restrict__ w1b,
                              const float* __restrict__ w2a, const float* __restrict__ w2b,
                              const float* __restrict__ w3a, const float* __restrict__ w3b,
                              bf16* __restrict__ wt) {
    int t = blockIdx.x * blockDim.x + threadIdx.x;
    const float* w; int K, N, base, r;
    if (t < 16384)       { w = w1a; K = 64;  N = 256; base = 0;      r = t; }
    else if (t < 81920)  { w = w1b; K = 256; N = 256; base = 16384;  r = t - 16384; }
    else if (t < 114688) { w = w2a; K = 256; N = 128; base = 81920;  r = t - 81920; }
    else if (t < 131072) { w = w2b; K = 128; N = 128; base = 114688; r = t - 114688; }
    else if (t < 139264) { w = w3a; K = 128; N = 64;  base = 131072; r = t - 131072; }
    else if (t < 143360) { w = w3b; K = 64;  N = 64;  base = 139264; r = t - 139264; }
    else return;
    int k = r % K, n = r / K;
    wt[base + r] = __float2bfloat16(w[(size_t)k * N + n]);
}

// edge-linear weights, transposed + K padded 16->32 with zeros: wep[col*32+k]
__global__ void conv_wep_kernel(const float* __restrict__ we1, const float* __restrict__ we2,
                                const float* __restrict__ we3, bf16* __restrict__ wep) {
    int t = blockIdx.x * blockDim.x + threadIdx.x;
    const float* w; int D, base, r;
    if (t < 2048)        { w = we1; D = 64;  base = 0;     r = t; }
    else if (t < 10240)  { w = we2; D = 256; base = 2048;  r = t - 2048; }
    else if (t < 14336)  { w = we3; D = 128; base = 10240; r = t - 10240; }
    else return;
    int k = r & 31, col = r >> 5;
    wep[base + r] = (k < 16) ? __float2bfloat16(w[(size_t)k * D + col]) : __float2bfloat16(0.f);
}

// ----------------------------------------------- message GEMM (CSR-ordered)
// msg[i][0..32) = relu( eab[elist[i]] @ we[:, c0..c0+32) + be + x[srcs[i]] )
// 16 CSR rows per wave via mfma_f32_16x16x32_bf16, K padded 16->32.
__global__ __launch_bounds__(256) void msg_gemm(
    const bf16* __restrict__ eab, const int* __restrict__ elist,
    const int* __restrict__ srcs, const bf16* __restrict__ x, int D, int c0,
    const bf16* __restrict__ wep, const float* __restrict__ be,
    bf16* __restrict__ msg, int E) {
    const int lane = threadIdx.x & 63;
    const int w = threadIdx.x >> 6;
    const int r16 = lane & 15;
    const int kg = lane >> 4;
    const long i0 = ((long)blockIdx.x * 4 + w) * 16;
    if (i0 >= E) return;

    const short* eap = (const short*)eab;
    const short* wpp = (const short*)wep;

    int row_l = (int)min(i0 + r16, (long)E - 1);
    int e = elist[row_l];
    short8v a = {0, 0, 0, 0, 0, 0, 0, 0};
    if (kg < 2) a = *(const short8v*)&eap[(size_t)e * 16 + kg * 8];

    f32x4 acc[2];
#pragma unroll
    for (int nt = 0; nt < 2; ++nt) {
        short8v b = *(const short8v*)&wpp[(size_t)(c0 + nt * 16 + r16) * 32 + kg * 8];
        acc[nt] = __builtin_amdgcn_mfma_f32_16x16x32_bf16(a, b,
                      (f32x4){0.f, 0.f, 0.f, 0.f}, 0, 0, 0);
    }

    int rows[4], ss[4];
#pragma unroll
    for (int r = 0; r < 4; ++r) {
        rows[r] = (int)(i0 + kg * 4 + r);
        ss[r] = srcs[min(rows[r], E - 1)];
    }
#pragma unroll
    for (int nt = 0; nt < 2; ++nt) {
        int col = c0 + nt * 16 + r16;
        float bs = be[col];
#pragma unroll
        for (int r = 0; r < 4; ++r) {
            if (rows[r] >= E) continue;
            float z = acc[nt][r] + bs +
                      __bfloat162float(x[(size_t)ss[r] * D + col]);
            z = fmaxf(z, 0.f);
            msg[(size_t)rows[r] * 32 + nt * 16 + r16] = __float2bfloat16(z);
        }
    }
}

// ------------------------------------------------- streaming aggregation
// t[n][c0+c] = x[n][c0+c] + sum_{i in [off[n],off[n+1])} msg[i][c]
__global__ __launch_bounds__(256) void agg_kernel(
    const bf16* __restrict__ msg, const int* __restrict__ off,
    const bf16* __restrict__ xin, int D, int c0, bf16* __restrict__ t, int N) {
    int tt = blockIdx.x * 256 + threadIdx.x;
    int n = tt >> 5;
    int c = tt & 31;
    if (n >= N) return;
    int i0 = off[n], i1 = off[n + 1];
    float acc = 0.f;
    int i = i0;
    for (; i + 4 <= i1; i += 4) {
        float a0 = __bfloat162float(msg[(size_t)(i + 0) * 32 + c]);
        float a1 = __bfloat162float(msg[(size_t)(i + 1) * 32 + c]);
        float a2 = __bfloat162float(msg[(size_t)(i + 2) * 32 + c]);
        float a3 = __bfloat162float(msg[(size_t)(i + 3) * 32 + c]);
        acc += (a0 + a1) + (a2 + a3);
    }
    for (; i < i1; ++i) acc += __bfloat162float(msg[(size_t)i * 32 + c]);
    int col = c0 + c;
    t[(size_t)n * D + col] =
        __float2bfloat16(__bfloat162float(xin[(size_t)n * D + col]) + acc);
}

// --------------------------------------------------------- bf16 MFMA GEMM
template <int NCOLS>
__global__ __launch_bounds__(256) void gemm_mfma(
    const bf16* __restrict__ A, const bf16* __restrict__ Wt,
    const float* __restrict__ bias, const float* __restrict__ bng,
    const float* __restrict__ bnb, const float* __restrict__ bnm,
    const float* __restrict__ bnv, bf16* __restrict__ C, int M, int K, int mode) {
    constexpr int NT = NCOLS / 16;
    const int lane = threadIdx.x & 63;
    const int w = threadIdx.x >> 6;
    const int mbase = blockIdx.x * 128 + w * 32;
    const int r16 = lane & 15;
    const int kg = lane >> 4;

    f32x4 acc[2][NT];
#pragma unroll
    for (int f = 0; f < 2; ++f)
#pragma unroll
        for (int nt = 0; nt < NT; ++nt) acc[f][nt] = (f32x4){0.f, 0.f, 0.f, 0.f};

    const short* Ap = (const short*)A;
    const short* Wp = (const short*)Wt;

    for (int k0 = 0; k0 < K; k0 += 32) {
        short8v a0 = *(const short8v*)&Ap[(size_t)(mbase + r16) * K + k0 + kg * 8];
        short8v a1 = *(const short8v*)&Ap[(size_t)(mbase + 16 + r16) * K + k0 + kg * 8];
#pragma unroll
        for (int nt = 0; nt < NT; ++nt) {
            short8v b = *(const short8v*)&Wp[(size_t)(nt * 16 + r16) * K + k0 + kg * 8];
            acc[0][nt] = __builtin_amdgcn_mfma_f32_16x16x32_bf16(a0, b, acc[0][nt], 0, 0, 0);
            acc[1][nt] = __builtin_amdgcn_mfma_f32_16x16x32_bf16(a1, b, acc[1][nt], 0, 0, 0);
        }
    }

#pragma unroll
    for (int nt = 0; nt < NT; ++nt) {
        int col = nt * 16 + r16;
        float bs = bias[col];
        float sc = 1.f, sh = 0.f;
        if (mode == 2) {
            sc = rsqrtf(bnv[col] + BN_EPS) * bng[col];
            sh = bnb[col] - bnm[col] * sc;
        }
#pragma unroll
        for (int f = 0; f < 2; ++f) {
#pragma unroll
            for (int rg = 0; rg < 4; ++rg) {
                int row = mbase + f * 16 + kg * 4 + rg;
                if (row >= M) continue;
                float z = acc[f][nt][rg] + bs;
                z = fmaxf(z, 0.f);
                if (mode == 2) z = z * sc + sh;
                C[(size_t)row * NCOLS + col] = __float2bfloat16(z);
            }
        }
    }
}

// ----------------------------------------------------------------- pooling
__global__ __launch_bounds__(256) void pool_kernel(const bf16* __restrict__ h,
                                                   const int* __restrict__ batch,
                                                   float* __restrict__ pooled, int N) {
    const int lane = threadIdx.x & 63;
    const int wid = blockIdx.x * 4 + (threadIdx.x >> 6);
    if (wid >= N) return;
    int g = batch[wid];
    g = min(max(g, 0), 127);
    atomicAdd(&pooled[g * 64 + lane], __bfloat162float(h[(size_t)wid * 64 + lane]));
}

// -------------------------------------------------------------------- head
__global__ __launch_bounds__(128) void head_kernel(
    const float* __restrict__ pooled, const float* __restrict__ w1,
    const float* __restrict__ b1, const float* __restrict__ w2,
    const float* __restrict__ b2, float* __restrict__ out) {
    const int g = threadIdx.x;
    float p[64];
#pragma unroll
    for (int i = 0; i < 64; ++i) p[i] = pooled[g * 64 + i];
    float o = b2[0];
#pragma unroll
    for (int j = 0; j < 16; ++j) {
        float hsum = b1[j];
#pragma unroll
        for (int i = 0; i < 64; ++i) hsum = fmaf(p[i], w1[i * 16 + j], hsum);
        o = fmaf(fmaxf(hsum, 0.f), w2[j], o);
    }
    out[g] = o;
}

// ------------------------------------------------------------------ launch
extern "C" void kernel_launch(void* const* d_in, const int* in_sizes, int n_in,
                              void* d_out, int out_size, void* d_ws,
                              size_t ws_size, hipStream_t stream) {
    const float* x     = (const float*)d_in[0];
    const float* ea    = (const float*)d_in[1];
    const int*   ei    = (const int*)d_in[2];
    const int*   batch = (const int*)d_in[3];
    const float* we1 = (const float*)d_in[4];
    const float* be1 = (const float*)d_in[5];
    const float* w1a = (const float*)d_in[6];
    const float* b1a = (const float*)d_in[7];
    const float* w1b = (const float*)d_in[8];
    const float* b1b = (const float*)d_in[9];
    const float* bn1g = (const float*)d_in[10];
    const float* bn1b = (const float*)d_in[11];
    const float* bn1m = (const float*)d_in[12];
    const float* bn1v = (const float*)d_in[13];
    const float* we2 = (const float*)d_in[14];
    const float* be2 = (const float*)d_in[15];
    const float* w2a = (const float*)d_in[16];
    const float* b2a = (const float*)d_in[17];
    const float* w2b = (const float*)d_in[18];
    const float* b2b = (const float*)d_in[19];
    const float* bn2g = (const float*)d_in[20];
    const float* bn2b = (const float*)d_in[21];
    const float* bn2m = (const float*)d_in[22];
    const float* bn2v = (const float*)d_in[23];
    const float* we3 = (const float*)d_in[24];
    const float* be3 = (const float*)d_in[25];
    const float* w3a = (const float*)d_in[26];
    const float* b3a = (const float*)d_in[27];
    const float* w3b = (const float*)d_in[28];
    const float* b3b = (const float*)d_in[29];
    const float* bn3g = (const float*)d_in[30];
    const float* bn3b = (const float*)d_in[31];
    const float* bn3m = (const float*)d_in[32];
    const float* bn3v = (const float*)d_in[33];
    const float* fc1w = (const float*)d_in[34];
    const float* fc1b = (const float*)d_in[35];
    const float* fc2w = (const float*)d_in[36];
    const float* fc2b = (const float*)d_in[37];

    const int N = in_sizes[0] / 64;
    const int E = in_sizes[1] / 16;
    const int M_pad = ((N + 127) / 128) * 128;
    const int* src = ei;
    const int* dst = ei + E;

    char* wsp = (char*)d_ws;
    auto alloc = [&](size_t bytes) -> void* {
        void* p = (void*)wsp;
        wsp += (bytes + 255) & ~(size_t)255;
        return p;
    };
    int* deg   = (int*)alloc((size_t)N * 4);
    int* off   = (int*)alloc((size_t)(N + 1) * 4);
    int* cur   = (int*)alloc((size_t)N * 4);
    int* elist = (int*)alloc((size_t)E * 4);
    int* srcs  = (int*)alloc((size_t)E * 4);
    bf16* xb   = (bf16*)alloc((size_t)N * 64 * 2);
    bf16* eab  = (bf16*)alloc((size_t)E * 16 * 2);
    bf16* tb   = (bf16*)alloc((size_t)M_pad * 256 * 2);
    bf16* hb   = (bf16*)alloc((size_t)M_pad * 256 * 2);
    // msg buffer (E x 32 bf16) aliased with ub (M_pad x 256 bf16)
    size_t big = (size_t)E * 32 * 2;
    size_t ubb = (size_t)M_pad * 256 * 2;
    bf16* msgb = (bf16*)alloc(big > ubb ? big : ubb);
    bf16* ub   = msgb;
    bf16* wt   = (bf16*)alloc((size_t)143360 * 2);
    bf16* wep  = (bf16*)alloc((size_t)14336 * 2);
    float* pooled = (float*)alloc(128 * 64 * 4);

    bf16* wt1a = wt + 0;
    bf16* wt1b = wt + 16384;
    bf16* wt2a = wt + 81920;
    bf16* wt2b = wt + 114688;
    bf16* wt3a = wt + 131072;
    bf16* wt3b = wt + 139264;
    bf16* wep1 = wep + 0;
    bf16* wep2 = wep + 2048;
    bf16* wep3 = wep + 10240;

    hipMemsetAsync(deg, 0, (size_t)N * 4, stream);
    hipMemsetAsync(pooled, 0, 128 * 64 * 4, stream);

    conv_bf16_kernel<<<(N * 64 / 4 + 255) / 256, 256, 0, stream>>>(x, xb, N * 64);
    conv_bf16_kernel<<<(E * 16 / 4 + 255) / 256, 256, 0, stream>>>(ea, eab, E * 16);
    conv_w_kernel<<<(143360 + 255) / 256, 256, 0, stream>>>(w1a, w1b, w2a, w2b,
                                                            w3a, w3b, wt);
    conv_wep_kernel<<<(14336 + 255) / 256, 256, 0, stream>>>(we1, we2, we3, wep);

    int eb = (E + 255) / 256;
    count_kernel<<<eb, 256, 0, stream>>>(dst, deg, E, N);
    scan_kernel<<<1, 1024, 0, stream>>>(deg, off, cur, N);
    fill_kernel<<<eb, 256, 0, stream>>>(src, dst, cur, elist, srcs, E, N);

    const int gblk = M_pad / 128;
    const int mgb = (E + 63) / 64;             // msg_gemm blocks
    const int agb = (N * 32 + 255) / 256;      // agg blocks

    // ---- layer 1 (64 -> 256)
    for (int c0 = 0; c0 < 64; c0 += 32) {
        msg_gemm<<<mgb, 256, 0, stream>>>(eab, elist, srcs, xb, 64, c0, wep1, be1,
                                          msgb, E);
        agg_kernel<<<agb, 256, 0, stream>>>(msgb, off, xb, 64, c0, tb, N);
    }
    gemm_mfma<256><<<gblk, 256, 0, stream>>>(tb, wt1a, b1a, nullptr, nullptr, nullptr,
                                             nullptr, ub, N, 64, 1);
    gemm_mfma<256><<<gblk, 256, 0, stream>>>(ub, wt1b, b1b, bn1g, bn1b, bn1m, bn1v,
                                             hb, N, 256, 2);
    // ---- layer 2 (256 -> 128)
    for (int c0 = 0; c0 < 256; c0 += 32) {
        msg_gemm<<<mgb, 256, 0, stream>>>(eab, elist, srcs, hb, 256, c0, wep2, be2,
                                          msgb, E);
        agg_kernel<<<agb, 256, 0, stream>>>(msgb, off, hb, 256, c0, tb, N);
    }
    gemm_mfma<128><<<gblk, 256, 0, stream>>>(tb, wt2a, b2a, nullptr, nullptr, nullptr,
                                             nullptr, ub, N, 256, 1);
    gemm_mfma<128><<<gblk, 256, 0, stream>>>(ub, wt2b, b2b, bn2g, bn2b, bn2m, bn2v,
                                             hb, N, 128, 2);
    // ---- layer 3 (128 -> 64)
    for (int c0 = 0; c0 < 128; c0 += 32) {
        msg_gemm<<<mgb, 256, 0, stream>>>(eab, elist, srcs, hb, 128, c0, wep3, be3,
                                          msgb, E);
        agg_kernel<<<agb, 256, 0, stream>>>(msgb, off, hb, 128, c0, tb, N);
    }
    gemm_mfma<64><<<gblk, 256, 0, stream>>>(tb, wt3a, b3a, nullptr, nullptr, nullptr,
                                            nullptr, ub, N, 128, 1);
    gemm_mfma<64><<<gblk, 256, 0, stream>>>(ub, wt3b, b3b, bn3g, bn3b, bn3m, bn3v,
                                            hb, N, 64, 2);

    // ---- pool + head
    pool_kernel<<<(N + 3) / 4, 256, 0, stream>>>(hb, batch, pooled, N);
    head_kernel<<<1, 128, 0, stream>>>(pooled, fc1w, fc1b, fc2w, fc2b, (float*)d_out);
}

// Round 4
// 573.502 us; speedup vs baseline: 2.2108x; 2.2108x over previous
//
#include <hip/hip_runtime.h>
#include <hip/hip_bf16.h>

#define BN_EPS 1e-5f

typedef __attribute__((ext_vector_type(8))) short short8v;
typedef __attribute__((ext_vector_type(4))) float f32x4;
typedef __hip_bfloat16 bf16;
typedef unsigned short ushort_t;

// ---------------------------------------------------------------- CSR build
__global__ void count_kernel(const int* __restrict__ dst, int* __restrict__ deg,
                             int E, int N) {
    int i = blockIdx.x * blockDim.x + threadIdx.x;
    if (i >= E) return;
    int d = dst[i];
    d = min(max(d, 0), N - 1);
    atomicAdd(&deg[d], 1);
}

// parallel scan: pass 1 — per-block sums (256 elems/block)
__global__ __launch_bounds__(256) void scan1_kernel(const int* __restrict__ deg,
                                                    int* __restrict__ bsum, int N) {
    int t = threadIdx.x, b = blockIdx.x;
    int i = b * 256 + t;
    int v = (i < N) ? deg[i] : 0;
#pragma unroll
    for (int d = 32; d; d >>= 1) v += __shfl_xor(v, d, 64);
    __shared__ int ws[4];
    if ((t & 63) == 0) ws[t >> 6] = v;
    __syncthreads();
    if (t == 0) bsum[b] = ws[0] + ws[1] + ws[2] + ws[3];
}

// pass 2 — exclusive scan of block sums (nb <= 256), one block
__global__ __launch_bounds__(256) void scan2_kernel(int* __restrict__ bsum, int nb) {
    int t = threadIdx.x;
    int v = (t < nb) ? bsum[t] : 0;
    int lane = t & 63, w = t >> 6;
    int inc = v;
#pragma unroll
    for (int d = 1; d < 64; d <<= 1) {
        int u = __shfl_up(inc, d, 64);
        if (lane >= d) inc += u;
    }
    __shared__ int ws[4];
    if (lane == 63) ws[w] = inc;
    __syncthreads();
    int base = 0;
    for (int j = 0; j < w; ++j) base += ws[j];
    if (t < nb) bsum[t] = base + inc - v;
}

// pass 3 — per-block exclusive scan + base -> off, cur; off[N] = E
__global__ __launch_bounds__(256) void scan3_kernel(const int* __restrict__ deg,
                                                    const int* __restrict__ bsum,
                                                    int* __restrict__ off,
                                                    int* __restrict__ cur, int N) {
    int t = threadIdx.x, b = blockIdx.x;
    int i = b * 256 + t;
    int v = (i < N) ? deg[i] : 0;
    int lane = t & 63, w = t >> 6;
    int inc = v;
#pragma unroll
    for (int d = 1; d < 64; d <<= 1) {
        int u = __shfl_up(inc, d, 64);
        if (lane >= d) inc += u;
    }
    __shared__ int ws[4];
    if (lane == 63) ws[w] = inc;
    __syncthreads();
    int base = bsum[b];
    for (int j = 0; j < w; ++j) base += ws[j];
    int excl = base + inc - v;
    if (i < N) { off[i] = excl; cur[i] = excl; }
    if (i == N - 1) off[N] = excl + v;
}

// fill: CSR edge placement; emits permuted src ids AND permuted edge_attr (f32)
__global__ void fill_kernel(const int* __restrict__ src, const int* __restrict__ dst,
                            const float* __restrict__ ea, int* __restrict__ cur,
                            int* __restrict__ srcs, float* __restrict__ eac,
                            int E, int N) {
    int i = blockIdx.x * blockDim.x + threadIdx.x;
    if (i >= E) return;
    int d = dst[i];
    d = min(max(d, 0), N - 1);
    int p = atomicAdd(&cur[d], 1);
    srcs[p] = min(max(src[i], 0), N - 1);
    float4 a0 = *(const float4*)&ea[(size_t)i * 16 + 0];
    float4 a1 = *(const float4*)&ea[(size_t)i * 16 + 4];
    float4 a2 = *(const float4*)&ea[(size_t)i * 16 + 8];
    float4 a3 = *(const float4*)&ea[(size_t)i * 16 + 12];
    *(float4*)&eac[(size_t)p * 16 + 0]  = a0;
    *(float4*)&eac[(size_t)p * 16 + 4]  = a1;
    *(float4*)&eac[(size_t)p * 16 + 8]  = a2;
    *(float4*)&eac[(size_t)p * 16 + 12] = a3;
}

// ---------------------------------------------------------- dtype converts
__global__ void conv_bf16_kernel(const float* __restrict__ in, bf16* __restrict__ out,
                                 int n) {
    int i = (blockIdx.x * blockDim.x + threadIdx.x) * 4;
    if (i + 3 < n) {
        float4 v = *(const float4*)&in[i];
        out[i + 0] = __float2bfloat16(v.x);
        out[i + 1] = __float2bfloat16(v.y);
        out[i + 2] = __float2bfloat16(v.z);
        out[i + 3] = __float2bfloat16(v.w);
    } else {
        for (int j = i; j < n && j >= 0; ++j) out[j] = __float2bfloat16(in[j]);
    }
}

// transpose+convert all 6 MLP weights: wt[base + n*K + k] = w[k*N + n]
__global__ void conv_w_kernel(const float* __restrict__ w1a, const float* __restrict__ w1b,
                              const float* __restrict__ w2a, const float* __restrict__ w2b,
                              const float* __restrict__ w3a, const float* __restrict__ w3b,
                              bf16* __restrict__ wt) {
    int t = blockIdx.x * blockDim.x + threadIdx.x;
    const float* w; int K, N, base, r;
    if (t < 16384)       { w = w1a; K = 64;  N = 256; base = 0;      r = t; }
    else if (t < 81920)  { w = w1b; K = 256; N = 256; base = 16384;  r = t - 16384; }
    else if (t < 114688) { w = w2a; K = 256; N = 128; base = 81920;  r = t - 81920; }
    else if (t < 131072) { w = w2b; K = 128; N = 128; base = 114688; r = t - 114688; }
    else if (t < 139264) { w = w3a; K = 128; N = 64;  base = 131072; r = t - 131072; }
    else if (t < 143360) { w = w3b; K = 64;  N = 64;  base = 139264; r = t - 139264; }
    else return;
    int k = r % K, n = r / K;
    wt[base + r] = __float2bfloat16(w[(size_t)k * N + n]);
}

// ------------------------------------------------- fused message + aggregate
// t[n] = x[n] + sum_{p in [off[n],off[n+1])} relu(x[srcs[p]] + eac[p] @ we + be)
// One wave per node; lane covers cols [lane*C, lane*C+C).
// srcs/eac reads are wave-uniform (scalar path); x gather is coalesced bf16.
template <int C>
__global__ __launch_bounds__(256) void msg_fused(
    const float* __restrict__ eac, const int* __restrict__ srcs,
    const int* __restrict__ off, const bf16* __restrict__ x,
    const float* __restrict__ we, const float* __restrict__ be,
    bf16* __restrict__ t, int N) {
    constexpr int D = C * 64;
    const int lane = threadIdx.x & 63;
    const int n = blockIdx.x * 4 + (threadIdx.x >> 6);
    if (n >= N) return;
    const int col0 = lane * C;

    float wreg[16][C];
#pragma unroll
    for (int k = 0; k < 16; ++k)
#pragma unroll
        for (int c = 0; c < C; ++c) wreg[k][c] = we[k * D + col0 + c];
    float breg[C];
#pragma unroll
    for (int c = 0; c < C; ++c) breg[c] = be[col0 + c];

    float acc[C];
#pragma unroll
    for (int c = 0; c < C; ++c) acc[c] = 0.f;

    const ushort_t* xp = (const ushort_t*)x;

    const int i0 = __builtin_amdgcn_readfirstlane(off[n]);
    const int i1 = __builtin_amdgcn_readfirstlane(off[n + 1]);

#define BF2F(u) (__builtin_bit_cast(float, (unsigned)(u) << 16))

    int i = i0;
    for (; i + 2 <= i1; i += 2) {
        const int s0 = __builtin_amdgcn_readfirstlane(srcs[i]);
        const int s1 = __builtin_amdgcn_readfirstlane(srcs[i + 1]);
        // x gathers (longest latency) issued first
        ushort_t xv0[C], xv1[C];
        if constexpr (C == 4) {
            *(ushort4*)xv0 = *(const ushort4*)&xp[(size_t)s0 * D + col0];
            *(ushort4*)xv1 = *(const ushort4*)&xp[(size_t)s1 * D + col0];
        } else if constexpr (C == 2) {
            *(ushort2*)xv0 = *(const ushort2*)&xp[(size_t)s0 * D + col0];
            *(ushort2*)xv1 = *(const ushort2*)&xp[(size_t)s1 * D + col0];
        } else {
            xv0[0] = xp[(size_t)s0 * D + col0];
            xv1[0] = xp[(size_t)s1 * D + col0];
        }
        // wave-uniform edge-attr rows (scalar loads)
        float e0[16], e1[16];
#pragma unroll
        for (int k = 0; k < 16; ++k) e0[k] = eac[(size_t)i * 16 + k];
#pragma unroll
        for (int k = 0; k < 16; ++k) e1[k] = eac[(size_t)(i + 1) * 16 + k];

        float m0[C], m1[C];
#pragma unroll
        for (int c = 0; c < C; ++c) { m0[c] = breg[c]; m1[c] = breg[c]; }
#pragma unroll
        for (int k = 0; k < 16; ++k) {
#pragma unroll
            for (int c = 0; c < C; ++c) {
                m0[c] = fmaf(e0[k], wreg[k][c], m0[c]);
                m1[c] = fmaf(e1[k], wreg[k][c], m1[c]);
            }
        }
#pragma unroll
        for (int c = 0; c < C; ++c)
            acc[c] += fmaxf(m0[c] + BF2F(xv0[c]), 0.f) +
                      fmaxf(m1[c] + BF2F(xv1[c]), 0.f);
    }
    for (; i < i1; ++i) {
        const int s0 = __builtin_amdgcn_readfirstlane(srcs[i]);
        ushort_t xv0[C];
        if constexpr (C == 4) {
            *(ushort4*)xv0 = *(const ushort4*)&xp[(size_t)s0 * D + col0];
        } else if constexpr (C == 2) {
            *(ushort2*)xv0 = *(const ushort2*)&xp[(size_t)s0 * D + col0];
        } else {
            xv0[0] = xp[(size_t)s0 * D + col0];
        }
        float e0[16];
#pragma unroll
        for (int k = 0; k < 16; ++k) e0[k] = eac[(size_t)i * 16 + k];
        float m0[C];
#pragma unroll
        for (int c = 0; c < C; ++c) m0[c] = breg[c];
#pragma unroll
        for (int k = 0; k < 16; ++k)
#pragma unroll
            for (int c = 0; c < C; ++c) m0[c] = fmaf(e0[k], wreg[k][c], m0[c]);
#pragma unroll
        for (int c = 0; c < C; ++c) acc[c] += fmaxf(m0[c] + BF2F(xv0[c]), 0.f);
    }

#pragma unroll
    for (int c = 0; c < C; ++c) {
        float xo = BF2F(xp[(size_t)n * D + col0 + c]);
        t[(size_t)n * D + col0 + c] = __float2bfloat16(xo + acc[c]);
    }
#undef BF2F
}

// --------------------------------------------------------- bf16 MFMA GEMM
template <int NCOLS>
__global__ __launch_bounds__(256) void gemm_mfma(
    const bf16* __restrict__ A, const bf16* __restrict__ Wt,
    const float* __restrict__ bias, const float* __restrict__ bng,
    const float* __restrict__ bnb, const float* __restrict__ bnm,
    const float* __restrict__ bnv, bf16* __restrict__ C, int M, int K, int mode) {
    constexpr int NT = NCOLS / 16;
    const int lane = threadIdx.x & 63;
    const int w = threadIdx.x >> 6;
    const int mbase = blockIdx.x * 128 + w * 32;
    const int r16 = lane & 15;
    const int kg = lane >> 4;

    f32x4 acc[2][NT];
#pragma unroll
    for (int f = 0; f < 2; ++f)
#pragma unroll
        for (int nt = 0; nt < NT; ++nt) acc[f][nt] = (f32x4){0.f, 0.f, 0.f, 0.f};

    const short* Ap = (const short*)A;
    const short* Wp = (const short*)Wt;

    for (int k0 = 0; k0 < K; k0 += 32) {
        short8v a0 = *(const short8v*)&Ap[(size_t)(mbase + r16) * K + k0 + kg * 8];
        short8v a1 = *(const short8v*)&Ap[(size_t)(mbase + 16 + r16) * K + k0 + kg * 8];
#pragma unroll
        for (int nt = 0; nt < NT; ++nt) {
            short8v b = *(const short8v*)&Wp[(size_t)(nt * 16 + r16) * K + k0 + kg * 8];
            acc[0][nt] = __builtin_amdgcn_mfma_f32_16x16x32_bf16(a0, b, acc[0][nt], 0, 0, 0);
            acc[1][nt] = __builtin_amdgcn_mfma_f32_16x16x32_bf16(a1, b, acc[1][nt], 0, 0, 0);
        }
    }

#pragma unroll
    for (int nt = 0; nt < NT; ++nt) {
        int col = nt * 16 + r16;
        float bs = bias[col];
        float sc = 1.f, sh = 0.f;
        if (mode == 2) {
            sc = rsqrtf(bnv[col] + BN_EPS) * bng[col];
            sh = bnb[col] - bnm[col] * sc;
        }
#pragma unroll
        for (int f = 0; f < 2; ++f) {
#pragma unroll
            for (int rg = 0; rg < 4; ++rg) {
                int row = mbase + f * 16 + kg * 4 + rg;
                if (row >= M) continue;
                float z = acc[f][nt][rg] + bs;
                z = fmaxf(z, 0.f);
                if (mode == 2) z = z * sc + sh;
                C[(size_t)row * NCOLS + col] = __float2bfloat16(z);
            }
        }
    }
}

// ----------------------------------------------------------------- pooling
__global__ __launch_bounds__(256) void pool_kernel(const bf16* __restrict__ h,
                                                   const int* __restrict__ batch,
                                                   float* __restrict__ pooled, int N) {
    const int lane = threadIdx.x & 63;
    const int wid = blockIdx.x * 4 + (threadIdx.x >> 6);
    if (wid >= N) return;
    int g = batch[wid];
    g = min(max(g, 0), 127);
    atomicAdd(&pooled[g * 64 + lane], __bfloat162float(h[(size_t)wid * 64 + lane]));
}

// -------------------------------------------------------------------- head
__global__ __launch_bounds__(128) void head_kernel(
    const float* __restrict__ pooled, const float* __restrict__ w1,
    const float* __restrict__ b1, const float* __restrict__ w2,
    const float* __restrict__ b2, float* __restrict__ out) {
    const int g = threadIdx.x;
    float p[64];
#pragma unroll
    for (int i = 0; i < 64; ++i) p[i] = pooled[g * 64 + i];
    float o = b2[0];
#pragma unroll
    for (int j = 0; j < 16; ++j) {
        float hsum = b1[j];
#pragma unroll
        for (int i = 0; i < 64; ++i) hsum = fmaf(p[i], w1[i * 16 + j], hsum);
        o = fmaf(fmaxf(hsum, 0.f), w2[j], o);
    }
    out[g] = o;
}

// ------------------------------------------------------------------ launch
extern "C" void kernel_launch(void* const* d_in, const int* in_sizes, int n_in,
                              void* d_out, int out_size, void* d_ws,
                              size_t ws_size, hipStream_t stream) {
    const float* x     = (const float*)d_in[0];
    const float* ea    = (const float*)d_in[1];
    const int*   ei    = (const int*)d_in[2];
    const int*   batch = (const int*)d_in[3];
    const float* we1 = (const float*)d_in[4];
    const float* be1 = (const float*)d_in[5];
    const float* w1a = (const float*)d_in[6];
    const float* b1a = (const float*)d_in[7];
    const float* w1b = (const float*)d_in[8];
    const float* b1b = (const float*)d_in[9];
    const float* bn1g = (const float*)d_in[10];
    const float* bn1b = (const float*)d_in[11];
    const float* bn1m = (const float*)d_in[12];
    const float* bn1v = (const float*)d_in[13];
    const float* we2 = (const float*)d_in[14];
    const float* be2 = (const float*)d_in[15];
    const float* w2a = (const float*)d_in[16];
    const float* b2a = (const float*)d_in[17];
    const float* w2b = (const float*)d_in[18];
    const float* b2b = (const float*)d_in[19];
    const float* bn2g = (const float*)d_in[20];
    const float* bn2b = (const float*)d_in[21];
    const float* bn2m = (const float*)d_in[22];
    const float* bn2v = (const float*)d_in[23];
    const float* we3 = (const float*)d_in[24];
    const float* be3 = (const float*)d_in[25];
    const float* w3a = (const float*)d_in[26];
    const float* b3a = (const float*)d_in[27];
    const float* w3b = (const float*)d_in[28];
    const float* b3b = (const float*)d_in[29];
    const float* bn3g = (const float*)d_in[30];
    const float* bn3b = (const float*)d_in[31];
    const float* bn3m = (const float*)d_in[32];
    const float* bn3v = (const float*)d_in[33];
    const float* fc1w = (const float*)d_in[34];
    const float* fc1b = (const float*)d_in[35];
    const float* fc2w = (const float*)d_in[36];
    const float* fc2b = (const float*)d_in[37];

    const int N = in_sizes[0] / 64;
    const int E = in_sizes[1] / 16;
    const int M_pad = ((N + 127) / 128) * 128;
    const int* src = ei;
    const int* dst = ei + E;

    char* wsp = (char*)d_ws;
    auto alloc = [&](size_t bytes) -> void* {
        void* p = (void*)wsp;
        wsp += (bytes + 255) & ~(size_t)255;
        return p;
    };
    const int nb = (N + 255) / 256;
    int* deg    = (int*)alloc((size_t)N * 4);
    int* off    = (int*)alloc((size_t)(N + 1) * 4);
    int* cur    = (int*)alloc((size_t)N * 4);
    int* bsum   = (int*)alloc((size_t)nb * 4);
    int* srcs   = (int*)alloc((size_t)E * 4);
    float* eac  = (float*)alloc((size_t)E * 16 * 4);
    bf16* xb    = (bf16*)alloc((size_t)N * 64 * 2);
    bf16* tb    = (bf16*)alloc((size_t)M_pad * 256 * 2);
    bf16* ub    = (bf16*)alloc((size_t)M_pad * 256 * 2);
    bf16* hb    = (bf16*)alloc((size_t)M_pad * 256 * 2);
    bf16* wt    = (bf16*)alloc((size_t)143360 * 2);
    float* pooled = (float*)alloc(128 * 64 * 4);

    bf16* wt1a = wt + 0;
    bf16* wt1b = wt + 16384;
    bf16* wt2a = wt + 81920;
    bf16* wt2b = wt + 114688;
    bf16* wt3a = wt + 131072;
    bf16* wt3b = wt + 139264;

    hipMemsetAsync(deg, 0, (size_t)N * 4, stream);
    hipMemsetAsync(pooled, 0, 128 * 64 * 4, stream);

    conv_bf16_kernel<<<(N * 64 / 4 + 255) / 256, 256, 0, stream>>>(x, xb, N * 64);
    conv_w_kernel<<<(143360 + 255) / 256, 256, 0, stream>>>(w1a, w1b, w2a, w2b,
                                                            w3a, w3b, wt);

    int eb = (E + 255) / 256;
    count_kernel<<<eb, 256, 0, stream>>>(dst, deg, E, N);
    scan1_kernel<<<nb, 256, 0, stream>>>(deg, bsum, N);
    scan2_kernel<<<1, 256, 0, stream>>>(bsum, nb);
    scan3_kernel<<<nb, 256, 0, stream>>>(deg, bsum, off, cur, N);
    fill_kernel<<<eb, 256, 0, stream>>>(src, dst, ea, cur, srcs, eac, E, N);

    const int gblk = M_pad / 128;
    const int mblk = (N + 3) / 4;

    // ---- layer 1 (64 -> 256)
    msg_fused<1><<<mblk, 256, 0, stream>>>(eac, srcs, off, xb, we1, be1, tb, N);
    gemm_mfma<256><<<gblk, 256, 0, stream>>>(tb, wt1a, b1a, nullptr, nullptr, nullptr,
                                             nullptr, ub, N, 64, 1);
    gemm_mfma<256><<<gblk, 256, 0, stream>>>(ub, wt1b, b1b, bn1g, bn1b, bn1m, bn1v,
                                             hb, N, 256, 2);
    // ---- layer 2 (256 -> 128)
    msg_fused<4><<<mblk, 256, 0, stream>>>(eac, srcs, off, hb, we2, be2, tb, N);
    gemm_mfma<128><<<gblk, 256, 0, stream>>>(tb, wt2a, b2a, nullptr, nullptr, nullptr,
                                             nullptr, ub, N, 256, 1);
    gemm_mfma<128><<<gblk, 256, 0, stream>>>(ub, wt2b, b2b, bn2g, bn2b, bn2m, bn2v,
                                             hb, N, 128, 2);
    // ---- layer 3 (128 -> 64)
    msg_fused<2><<<mblk, 256, 0, stream>>>(eac, srcs, off, hb, we3, be3, tb, N);
    gemm_mfma<64><<<gblk, 256, 0, stream>>>(tb, wt3a, b3a, nullptr, nullptr, nullptr,
                                            nullptr, ub, N, 128, 1);
    gemm_mfma<64><<<gblk, 256, 0, stream>>>(ub, wt3b, b3b, bn3g, bn3b, bn3m, bn3v,
                                            hb, N, 64, 2);

    // ---- pool + head
    pool_kernel<<<(N + 3) / 4, 256, 0, stream>>>(hb, batch, pooled, N);
    head_kernel<<<1, 128, 0, stream>>>(pooled, fc1w, fc1b, fc2w, fc2b, (float*)d_out);
}

// Round 5
// 514.022 us; speedup vs baseline: 2.4666x; 1.1157x over previous
//
#include <hip/hip_runtime.h>
#include <hip/hip_bf16.h>

#define BN_EPS 1e-5f

typedef __attribute__((ext_vector_type(8))) short short8v;
typedef __attribute__((ext_vector_type(4))) float f32x4;
typedef _Float16 f16x2 __attribute__((ext_vector_type(2)));
typedef __hip_bfloat16 bf16;
typedef unsigned short ushort_t;
typedef unsigned int uint_t;

// ---------------------------------------------------------------- CSR build
__global__ void count_kernel(const int* __restrict__ dst, int* __restrict__ deg,
                             int E, int N) {
    int i = blockIdx.x * blockDim.x + threadIdx.x;
    if (i >= E) return;
    int d = dst[i];
    d = min(max(d, 0), N - 1);
    atomicAdd(&deg[d], 1);
}

// parallel scan: pass 1 — per-block sums (256 elems/block)
__global__ __launch_bounds__(256) void scan1_kernel(const int* __restrict__ deg,
                                                    int* __restrict__ bsum, int N) {
    int t = threadIdx.x, b = blockIdx.x;
    int i = b * 256 + t;
    int v = (i < N) ? deg[i] : 0;
#pragma unroll
    for (int d = 32; d; d >>= 1) v += __shfl_xor(v, d, 64);
    __shared__ int ws[4];
    if ((t & 63) == 0) ws[t >> 6] = v;
    __syncthreads();
    if (t == 0) bsum[b] = ws[0] + ws[1] + ws[2] + ws[3];
}

// pass 2 — exclusive scan of block sums (nb <= 256), one block
__global__ __launch_bounds__(256) void scan2_kernel(int* __restrict__ bsum, int nb) {
    int t = threadIdx.x;
    int v = (t < nb) ? bsum[t] : 0;
    int lane = t & 63, w = t >> 6;
    int inc = v;
#pragma unroll
    for (int d = 1; d < 64; d <<= 1) {
        int u = __shfl_up(inc, d, 64);
        if (lane >= d) inc += u;
    }
    __shared__ int ws[4];
    if (lane == 63) ws[w] = inc;
    __syncthreads();
    int base = 0;
    for (int j = 0; j < w; ++j) base += ws[j];
    if (t < nb) bsum[t] = base + inc - v;
}

// pass 3 — per-block exclusive scan + base -> off, cur; off[N] = E
__global__ __launch_bounds__(256) void scan3_kernel(const int* __restrict__ deg,
                                                    const int* __restrict__ bsum,
                                                    int* __restrict__ off,
                                                    int* __restrict__ cur, int N) {
    int t = threadIdx.x, b = blockIdx.x;
    int i = b * 256 + t;
    int v = (i < N) ? deg[i] : 0;
    int lane = t & 63, w = t >> 6;
    int inc = v;
#pragma unroll
    for (int d = 1; d < 64; d <<= 1) {
        int u = __shfl_up(inc, d, 64);
        if (lane >= d) inc += u;
    }
    __shared__ int ws[4];
    if (lane == 63) ws[w] = inc;
    __syncthreads();
    int base = bsum[b];
    for (int j = 0; j < w; ++j) base += ws[j];
    int excl = base + inc - v;
    if (i < N) { off[i] = excl; cur[i] = excl; }
    if (i == N - 1) off[N] = excl + v;
}

// fill: CSR edge placement; emits permuted src ids AND permuted edge_attr
// packed as 8 x (2 x f16) per edge
__global__ void fill_kernel(const int* __restrict__ src, const int* __restrict__ dst,
                            const float* __restrict__ ea, int* __restrict__ cur,
                            int* __restrict__ srcs, uint_t* __restrict__ each,
                            int E, int N) {
    int i = blockIdx.x * blockDim.x + threadIdx.x;
    if (i >= E) return;
    int d = dst[i];
    d = min(max(d, 0), N - 1);
    int p = atomicAdd(&cur[d], 1);
    srcs[p] = min(max(src[i], 0), N - 1);
    uint_t pk[8];
#pragma unroll
    for (int q = 0; q < 4; ++q) {
        float4 a = *(const float4*)&ea[(size_t)i * 16 + q * 4];
        f16x2 h0 = {(_Float16)a.x, (_Float16)a.y};
        f16x2 h1 = {(_Float16)a.z, (_Float16)a.w};
        pk[q * 2 + 0] = __builtin_bit_cast(uint_t, h0);
        pk[q * 2 + 1] = __builtin_bit_cast(uint_t, h1);
    }
    *(uint4*)&each[(size_t)p * 8 + 0] = *(uint4*)&pk[0];
    *(uint4*)&each[(size_t)p * 8 + 4] = *(uint4*)&pk[4];
}

// ---------------------------------------------------------- dtype converts
__global__ void conv_bf16_kernel(const float* __restrict__ in, bf16* __restrict__ out,
                                 int n) {
    int i = (blockIdx.x * blockDim.x + threadIdx.x) * 4;
    if (i + 3 < n) {
        float4 v = *(const float4*)&in[i];
        out[i + 0] = __float2bfloat16(v.x);
        out[i + 1] = __float2bfloat16(v.y);
        out[i + 2] = __float2bfloat16(v.z);
        out[i + 3] = __float2bfloat16(v.w);
    } else {
        for (int j = i; j < n && j >= 0; ++j) out[j] = __float2bfloat16(in[j]);
    }
}

// transpose+convert all 6 MLP weights: wt[base + n*K + k] = w[k*N + n]
__global__ void conv_w_kernel(const float* __restrict__ w1a, const float* __restrict__ w1b,
                              const float* __restrict__ w2a, const float* __restrict__ w2b,
                              const float* __restrict__ w3a, const float* __restrict__ w3b,
                              bf16* __restrict__ wt) {
    int t = blockIdx.x * blockDim.x + threadIdx.x;
    const float* w; int K, N, base, r;
    if (t < 16384)       { w = w1a; K = 64;  N = 256; base = 0;      r = t; }
    else if (t < 81920)  { w = w1b; K = 256; N = 256; base = 16384;  r = t - 16384; }
    else if (t < 114688) { w = w2a; K = 256; N = 128; base = 81920;  r = t - 81920; }
    else if (t < 131072) { w = w2b; K = 128; N = 128; base = 114688; r = t - 114688; }
    else if (t < 139264) { w = w3a; K = 128; N = 64;  base = 131072; r = t - 131072; }
    else if (t < 143360) { w = w3b; K = 64;  N = 64;  base = 139264; r = t - 139264; }
    else return;
    int k = r % K, n = r / K;
    wt[base + r] = __float2bfloat16(w[(size_t)k * N + n]);
}

// edge-linear weights as packed f16 k-pairs: wef[base + p*D + col] = (w[2p][col], w[2p+1][col])
__global__ void conv_wef_kernel(const float* __restrict__ we1, const float* __restrict__ we2,
                                const float* __restrict__ we3, uint_t* __restrict__ wef) {
    int t = blockIdx.x * blockDim.x + threadIdx.x;
    const float* w; int D, base, r;
    if (t < 512)        { w = we1; D = 64;  base = 0;    r = t; }
    else if (t < 2560)  { w = we2; D = 256; base = 512;  r = t - 512; }
    else if (t < 3584)  { w = we3; D = 128; base = 2560; r = t - 2560; }
    else return;
    int p = r / D, col = r % D;
    f16x2 h = {(_Float16)w[(size_t)(2 * p) * D + col],
               (_Float16)w[(size_t)(2 * p + 1) * D + col]};
    wef[base + r] = __builtin_bit_cast(uint_t, h);
}

// ------------------------------------------------- fused message + aggregate
// t[n] = x[n] + sum_{p in [off[n],off[n+1])} relu(x[srcs[p]] + e[p] @ we + be)
// One wave per node; lane covers cols [lane*C, lane*C+C).
// Edge-MLP via v_dot2_f32_f16 on packed f16 pairs (wave-uniform e operand).
template <int C>
__global__ __launch_bounds__(256) void msg_fused(
    const uint_t* __restrict__ each, const int* __restrict__ srcs,
    const int* __restrict__ off, const bf16* __restrict__ x,
    const uint_t* __restrict__ wef, const float* __restrict__ be,
    bf16* __restrict__ t, int N) {
    constexpr int D = C * 64;
    const int lane = threadIdx.x & 63;
    const int n = blockIdx.x * 4 + (threadIdx.x >> 6);
    if (n >= N) return;
    const int col0 = lane * C;

    uint_t wreg[8][C];
#pragma unroll
    for (int p = 0; p < 8; ++p)
#pragma unroll
        for (int c = 0; c < C; ++c) wreg[p][c] = wef[p * D + col0 + c];
    float breg[C];
#pragma unroll
    for (int c = 0; c < C; ++c) breg[c] = be[col0 + c];

    float acc[C];
#pragma unroll
    for (int c = 0; c < C; ++c) acc[c] = 0.f;

    const ushort_t* xp = (const ushort_t*)x;

    const int i0 = __builtin_amdgcn_readfirstlane(off[n]);
    const int i1 = __builtin_amdgcn_readfirstlane(off[n + 1]);

#define BF2F(u) (__builtin_bit_cast(float, (unsigned)(u) << 16))
#define H2(u) (__builtin_bit_cast(f16x2, u))

    int i = i0;
    for (; i + 2 <= i1; i += 2) {
        const int s0 = __builtin_amdgcn_readfirstlane(srcs[i]);
        const int s1 = __builtin_amdgcn_readfirstlane(srcs[i + 1]);
        // x gathers (longest latency) issued first
        ushort_t xv0[C], xv1[C];
        if constexpr (C == 4) {
            *(ushort4*)xv0 = *(const ushort4*)&xp[(size_t)s0 * D + col0];
            *(ushort4*)xv1 = *(const ushort4*)&xp[(size_t)s1 * D + col0];
        } else if constexpr (C == 2) {
            *(ushort2*)xv0 = *(const ushort2*)&xp[(size_t)s0 * D + col0];
            *(ushort2*)xv1 = *(const ushort2*)&xp[(size_t)s1 * D + col0];
        } else {
            xv0[0] = xp[(size_t)s0 * D + col0];
            xv1[0] = xp[(size_t)s1 * D + col0];
        }
        // wave-uniform packed edge-attr pairs (scalar loads)
        uint_t e0[8], e1[8];
#pragma unroll
        for (int p = 0; p < 8; ++p) e0[p] = each[(size_t)i * 8 + p];
#pragma unroll
        for (int p = 0; p < 8; ++p) e1[p] = each[(size_t)(i + 1) * 8 + p];

        float m0[C], m1[C];
#pragma unroll
        for (int c = 0; c < C; ++c) {
            m0[c] = __builtin_amdgcn_fdot2(H2(e0[0]), H2(wreg[0][c]), breg[c], false);
            m1[c] = __builtin_amdgcn_fdot2(H2(e1[0]), H2(wreg[0][c]), breg[c], false);
        }
#pragma unroll
        for (int p = 1; p < 8; ++p) {
#pragma unroll
            for (int c = 0; c < C; ++c) {
                m0[c] = __builtin_amdgcn_fdot2(H2(e0[p]), H2(wreg[p][c]), m0[c], false);
                m1[c] = __builtin_amdgcn_fdot2(H2(e1[p]), H2(wreg[p][c]), m1[c], false);
            }
        }
#pragma unroll
        for (int c = 0; c < C; ++c)
            acc[c] += fmaxf(m0[c] + BF2F(xv0[c]), 0.f) +
                      fmaxf(m1[c] + BF2F(xv1[c]), 0.f);
    }
    for (; i < i1; ++i) {
        const int s0 = __builtin_amdgcn_readfirstlane(srcs[i]);
        ushort_t xv0[C];
        if constexpr (C == 4) {
            *(ushort4*)xv0 = *(const ushort4*)&xp[(size_t)s0 * D + col0];
        } else if constexpr (C == 2) {
            *(ushort2*)xv0 = *(const ushort2*)&xp[(size_t)s0 * D + col0];
        } else {
            xv0[0] = xp[(size_t)s0 * D + col0];
        }
        uint_t e0[8];
#pragma unroll
        for (int p = 0; p < 8; ++p) e0[p] = each[(size_t)i * 8 + p];
        float m0[C];
#pragma unroll
        for (int c = 0; c < C; ++c)
            m0[c] = __builtin_amdgcn_fdot2(H2(e0[0]), H2(wreg[0][c]), breg[c], false);
#pragma unroll
        for (int p = 1; p < 8; ++p)
#pragma unroll
            for (int c = 0; c < C; ++c)
                m0[c] = __builtin_amdgcn_fdot2(H2(e0[p]), H2(wreg[p][c]), m0[c], false);
#pragma unroll
        for (int c = 0; c < C; ++c) acc[c] += fmaxf(m0[c] + BF2F(xv0[c]), 0.f);
    }

#pragma unroll
    for (int c = 0; c < C; ++c) {
        float xo = BF2F(xp[(size_t)n * D + col0 + c]);
        t[(size_t)n * D + col0 + c] = __float2bfloat16(xo + acc[c]);
    }
#undef BF2F
#undef H2
}

// --------------------------------------------------------- bf16 MFMA GEMM
template <int NCOLS>
__global__ __launch_bounds__(256) void gemm_mfma(
    const bf16* __restrict__ A, const bf16* __restrict__ Wt,
    const float* __restrict__ bias, const float* __restrict__ bng,
    const float* __restrict__ bnb, const float* __restrict__ bnm,
    const float* __restrict__ bnv, bf16* __restrict__ C, int M, int K, int mode) {
    constexpr int NT = NCOLS / 16;
    const int lane = threadIdx.x & 63;
    const int w = threadIdx.x >> 6;
    const int mbase = blockIdx.x * 128 + w * 32;
    const int r16 = lane & 15;
    const int kg = lane >> 4;

    f32x4 acc[2][NT];
#pragma unroll
    for (int f = 0; f < 2; ++f)
#pragma unroll
        for (int nt = 0; nt < NT; ++nt) acc[f][nt] = (f32x4){0.f, 0.f, 0.f, 0.f};

    const short* Ap = (const short*)A;
    const short* Wp = (const short*)Wt;

    for (int k0 = 0; k0 < K; k0 += 32) {
        short8v a0 = *(const short8v*)&Ap[(size_t)(mbase + r16) * K + k0 + kg * 8];
        short8v a1 = *(const short8v*)&Ap[(size_t)(mbase + 16 + r16) * K + k0 + kg * 8];
#pragma unroll
        for (int nt = 0; nt < NT; ++nt) {
            short8v b = *(const short8v*)&Wp[(size_t)(nt * 16 + r16) * K + k0 + kg * 8];
            acc[0][nt] = __builtin_amdgcn_mfma_f32_16x16x32_bf16(a0, b, acc[0][nt], 0, 0, 0);
            acc[1][nt] = __builtin_amdgcn_mfma_f32_16x16x32_bf16(a1, b, acc[1][nt], 0, 0, 0);
        }
    }

#pragma unroll
    for (int nt = 0; nt < NT; ++nt) {
        int col = nt * 16 + r16;
        float bs = bias[col];
        float sc = 1.f, sh = 0.f;
        if (mode == 2) {
            sc = rsqrtf(bnv[col] + BN_EPS) * bng[col];
            sh = bnb[col] - bnm[col] * sc;
        }
#pragma unroll
        for (int f = 0; f < 2; ++f) {
#pragma unroll
            for (int rg = 0; rg < 4; ++rg) {
                int row = mbase + f * 16 + kg * 4 + rg;
                if (row >= M) continue;
                float z = acc[f][nt][rg] + bs;
                z = fmaxf(z, 0.f);
                if (mode == 2) z = z * sc + sh;
                C[(size_t)row * NCOLS + col] = __float2bfloat16(z);
            }
        }
    }
}

// ----------------------------------------------------------------- pooling
__global__ __launch_bounds__(256) void pool_kernel(const bf16* __restrict__ h,
                                                   const int* __restrict__ batch,
                                                   float* __restrict__ pooled, int N) {
    const int lane = threadIdx.x & 63;
    const int wid = blockIdx.x * 4 + (threadIdx.x >> 6);
    if (wid >= N) return;
    int g = batch[wid];
    g = min(max(g, 0), 127);
    atomicAdd(&pooled[g * 64 + lane], __bfloat162float(h[(size_t)wid * 64 + lane]));
}

// -------------------------------------------------------------------- head
__global__ __launch_bounds__(128) void head_kernel(
    const float* __restrict__ pooled, const float* __restrict__ w1,
    const float* __restrict__ b1, const float* __restrict__ w2,
    const float* __restrict__ b2, float* __restrict__ out) {
    const int g = threadIdx.x;
    float p[64];
#pragma unroll
    for (int i = 0; i < 64; ++i) p[i] = pooled[g * 64 + i];
    float o = b2[0];
#pragma unroll
    for (int j = 0; j < 16; ++j) {
        float hsum = b1[j];
#pragma unroll
        for (int i = 0; i < 64; ++i) hsum = fmaf(p[i], w1[i * 16 + j], hsum);
        o = fmaf(fmaxf(hsum, 0.f), w2[j], o);
    }
    out[g] = o;
}

// ------------------------------------------------------------------ launch
extern "C" void kernel_launch(void* const* d_in, const int* in_sizes, int n_in,
                              void* d_out, int out_size, void* d_ws,
                              size_t ws_size, hipStream_t stream) {
    const float* x     = (const float*)d_in[0];
    const float* ea    = (const float*)d_in[1];
    const int*   ei    = (const int*)d_in[2];
    const int*   batch = (const int*)d_in[3];
    const float* we1 = (const float*)d_in[4];
    const float* be1 = (const float*)d_in[5];
    const float* w1a = (const float*)d_in[6];
    const float* b1a = (const float*)d_in[7];
    const float* w1b = (const float*)d_in[8];
    const float* b1b = (const float*)d_in[9];
    const float* bn1g = (const float*)d_in[10];
    const float* bn1b = (const float*)d_in[11];
    const float* bn1m = (const float*)d_in[12];
    const float* bn1v = (const float*)d_in[13];
    const float* we2 = (const float*)d_in[14];
    const float* be2 = (const float*)d_in[15];
    const float* w2a = (const float*)d_in[16];
    const float* b2a = (const float*)d_in[17];
    const float* w2b = (const float*)d_in[18];
    const float* b2b = (const float*)d_in[19];
    const float* bn2g = (const float*)d_in[20];
    const float* bn2b = (const float*)d_in[21];
    const float* bn2m = (const float*)d_in[22];
    const float* bn2v = (const float*)d_in[23];
    const float* we3 = (const float*)d_in[24];
    const float* be3 = (const float*)d_in[25];
    const float* w3a = (const float*)d_in[26];
    const float* b3a = (const float*)d_in[27];
    const float* w3b = (const float*)d_in[28];
    const float* b3b = (const float*)d_in[29];
    const float* bn3g = (const float*)d_in[30];
    const float* bn3b = (const float*)d_in[31];
    const float* bn3m = (const float*)d_in[32];
    const float* bn3v = (const float*)d_in[33];
    const float* fc1w = (const float*)d_in[34];
    const float* fc1b = (const float*)d_in[35];
    const float* fc2w = (const float*)d_in[36];
    const float* fc2b = (const float*)d_in[37];

    const int N = in_sizes[0] / 64;
    const int E = in_sizes[1] / 16;
    const int M_pad = ((N + 127) / 128) * 128;
    const int* src = ei;
    const int* dst = ei + E;

    char* wsp = (char*)d_ws;
    auto alloc = [&](size_t bytes) -> void* {
        void* p = (void*)wsp;
        wsp += (bytes + 255) & ~(size_t)255;
        return p;
    };
    const int nb = (N + 255) / 256;
    int* deg    = (int*)alloc((size_t)N * 4);
    int* off    = (int*)alloc((size_t)(N + 1) * 4);
    int* cur    = (int*)alloc((size_t)N * 4);
    int* bsum   = (int*)alloc((size_t)nb * 4);
    int* srcs   = (int*)alloc((size_t)E * 4);
    uint_t* each = (uint_t*)alloc((size_t)E * 8 * 4);
    bf16* xb    = (bf16*)alloc((size_t)N * 64 * 2);
    bf16* tb    = (bf16*)alloc((size_t)M_pad * 256 * 2);
    bf16* ub    = (bf16*)alloc((size_t)M_pad * 256 * 2);
    bf16* hb    = (bf16*)alloc((size_t)M_pad * 256 * 2);
    bf16* wt    = (bf16*)alloc((size_t)143360 * 2);
    uint_t* wef = (uint_t*)alloc((size_t)3584 * 4);
    float* pooled = (float*)alloc(128 * 64 * 4);

    bf16* wt1a = wt + 0;
    bf16* wt1b = wt + 16384;
    bf16* wt2a = wt + 81920;
    bf16* wt2b = wt + 114688;
    bf16* wt3a = wt + 131072;
    bf16* wt3b = wt + 139264;
    uint_t* wef1 = wef + 0;
    uint_t* wef2 = wef + 512;
    uint_t* wef3 = wef + 2560;

    hipMemsetAsync(deg, 0, (size_t)N * 4, stream);
    hipMemsetAsync(pooled, 0, 128 * 64 * 4, stream);

    conv_bf16_kernel<<<(N * 64 / 4 + 255) / 256, 256, 0, stream>>>(x, xb, N * 64);
    conv_w_kernel<<<(143360 + 255) / 256, 256, 0, stream>>>(w1a, w1b, w2a, w2b,
                                                            w3a, w3b, wt);
    conv_wef_kernel<<<(3584 + 255) / 256, 256, 0, stream>>>(we1, we2, we3, wef);

    int eb = (E + 255) / 256;
    count_kernel<<<eb, 256, 0, stream>>>(dst, deg, E, N);
    scan1_kernel<<<nb, 256, 0, stream>>>(deg, bsum, N);
    scan2_kernel<<<1, 256, 0, stream>>>(bsum, nb);
    scan3_kernel<<<nb, 256, 0, stream>>>(deg, bsum, off, cur, N);
    fill_kernel<<<eb, 256, 0, stream>>>(src, dst, ea, cur, srcs, each, E, N);

    const int gblk = M_pad / 128;
    const int mblk = (N + 3) / 4;

    // ---- layer 1 (64 -> 256)
    msg_fused<1><<<mblk, 256, 0, stream>>>(each, srcs, off, xb, wef1, be1, tb, N);
    gemm_mfma<256><<<gblk, 256, 0, stream>>>(tb, wt1a, b1a, nullptr, nullptr, nullptr,
                                             nullptr, ub, N, 64, 1);
    gemm_mfma<256><<<gblk, 256, 0, stream>>>(ub, wt1b, b1b, bn1g, bn1b, bn1m, bn1v,
                                             hb, N, 256, 2);
    // ---- layer 2 (256 -> 128)
    msg_fused<4><<<mblk, 256, 0, stream>>>(each, srcs, off, hb, wef2, be2, tb, N);
    gemm_mfma<128><<<gblk, 256, 0, stream>>>(tb, wt2a, b2a, nullptr, nullptr, nullptr,
                                             nullptr, ub, N, 256, 1);
    gemm_mfma<128><<<gblk, 256, 0, stream>>>(ub, wt2b, b2b, bn2g, bn2b, bn2m, bn2v,
                                             hb, N, 128, 2);
    // ---- layer 3 (128 -> 64)
    msg_fused<2><<<mblk, 256, 0, stream>>>(each, srcs, off, hb, wef3, be3, tb, N);
    gemm_mfma<64><<<gblk, 256, 0, stream>>>(tb, wt3a, b3a, nullptr, nullptr, nullptr,
                                            nullptr, ub, N, 128, 1);
    gemm_mfma<64><<<gblk, 256, 0, stream>>>(ub, wt3b, b3b, bn3g, bn3b, bn3m, bn3v,
                                            hb, N, 64, 2);

    // ---- pool + head
    pool_kernel<<<(N + 3) / 4, 256, 0, stream>>>(hb, batch, pooled, N);
    head_kernel<<<1, 128, 0, stream>>>(pooled, fc1w, fc1b, fc2w, fc2b, (float*)d_out);
}

// Round 6
// 490.814 us; speedup vs baseline: 2.5832x; 1.0473x over previous
//
#include <hip/hip_runtime.h>
#include <hip/hip_bf16.h>

#define BN_EPS 1e-5f

typedef __attribute__((ext_vector_type(8))) short short8v;
typedef __attribute__((ext_vector_type(4))) float f32x4;
typedef _Float16 f16x2 __attribute__((ext_vector_type(2)));
typedef __hip_bfloat16 bf16;
typedef unsigned short ushort_t;
typedef unsigned int uint_t;

// ---------------------------------------------------------------- CSR build
__global__ void count_kernel(const int* __restrict__ dst, int* __restrict__ deg,
                             int E, int N) {
    int i = blockIdx.x * blockDim.x + threadIdx.x;
    if (i >= E) return;
    int d = dst[i];
    d = min(max(d, 0), N - 1);
    atomicAdd(&deg[d], 1);
}

// parallel scan: pass 1 — per-block sums (256 elems/block)
__global__ __launch_bounds__(256) void scan1_kernel(const int* __restrict__ deg,
                                                    int* __restrict__ bsum, int N) {
    int t = threadIdx.x, b = blockIdx.x;
    int i = b * 256 + t;
    int v = (i < N) ? deg[i] : 0;
#pragma unroll
    for (int d = 32; d; d >>= 1) v += __shfl_xor(v, d, 64);
    __shared__ int ws[4];
    if ((t & 63) == 0) ws[t >> 6] = v;
    __syncthreads();
    if (t == 0) bsum[b] = ws[0] + ws[1] + ws[2] + ws[3];
}

// pass 2 — exclusive scan of block sums (nb <= 256), one block
__global__ __launch_bounds__(256) void scan2_kernel(int* __restrict__ bsum, int nb) {
    int t = threadIdx.x;
    int v = (t < nb) ? bsum[t] : 0;
    int lane = t & 63, w = t >> 6;
    int inc = v;
#pragma unroll
    for (int d = 1; d < 64; d <<= 1) {
        int u = __shfl_up(inc, d, 64);
        if (lane >= d) inc += u;
    }
    __shared__ int ws[4];
    if (lane == 63) ws[w] = inc;
    __syncthreads();
    int base = 0;
    for (int j = 0; j < w; ++j) base += ws[j];
    if (t < nb) bsum[t] = base + inc - v;
}

// pass 3 — per-block exclusive scan + base -> off, cur; off[N] = E
__global__ __launch_bounds__(256) void scan3_kernel(const int* __restrict__ deg,
                                                    const int* __restrict__ bsum,
                                                    int* __restrict__ off,
                                                    int* __restrict__ cur, int N) {
    int t = threadIdx.x, b = blockIdx.x;
    int i = b * 256 + t;
    int v = (i < N) ? deg[i] : 0;
    int lane = t & 63, w = t >> 6;
    int inc = v;
#pragma unroll
    for (int d = 1; d < 64; d <<= 1) {
        int u = __shfl_up(inc, d, 64);
        if (lane >= d) inc += u;
    }
    __shared__ int ws[4];
    if (lane == 63) ws[w] = inc;
    __syncthreads();
    int base = bsum[b];
    for (int j = 0; j < w; ++j) base += ws[j];
    int excl = base + inc - v;
    if (i < N) { off[i] = excl; cur[i] = excl; }
    if (i == N - 1) off[N] = excl + v;
}

// fill: CSR edge placement; emits permuted src ids AND permuted edge_attr
// packed as 8 x (2 x f16) per edge
__global__ void fill_kernel(const int* __restrict__ src, const int* __restrict__ dst,
                            const float* __restrict__ ea, int* __restrict__ cur,
                            int* __restrict__ srcs, uint_t* __restrict__ each,
                            int E, int N) {
    int i = blockIdx.x * blockDim.x + threadIdx.x;
    if (i >= E) return;
    int d = dst[i];
    d = min(max(d, 0), N - 1);
    int p = atomicAdd(&cur[d], 1);
    srcs[p] = min(max(src[i], 0), N - 1);
    uint_t pk[8];
#pragma unroll
    for (int q = 0; q < 4; ++q) {
        float4 a = *(const float4*)&ea[(size_t)i * 16 + q * 4];
        f16x2 h0 = {(_Float16)a.x, (_Float16)a.y};
        f16x2 h1 = {(_Float16)a.z, (_Float16)a.w};
        pk[q * 2 + 0] = __builtin_bit_cast(uint_t, h0);
        pk[q * 2 + 1] = __builtin_bit_cast(uint_t, h1);
    }
    *(uint4*)&each[(size_t)p * 8 + 0] = *(uint4*)&pk[0];
    *(uint4*)&each[(size_t)p * 8 + 4] = *(uint4*)&pk[4];
}

// ---------------------------------------------------------- dtype converts
__global__ void conv_bf16_kernel(const float* __restrict__ in, bf16* __restrict__ out,
                                 int n) {
    int i = (blockIdx.x * blockDim.x + threadIdx.x) * 4;
    if (i + 3 < n) {
        float4 v = *(const float4*)&in[i];
        out[i + 0] = __float2bfloat16(v.x);
        out[i + 1] = __float2bfloat16(v.y);
        out[i + 2] = __float2bfloat16(v.z);
        out[i + 3] = __float2bfloat16(v.w);
    } else {
        for (int j = i; j < n && j >= 0; ++j) out[j] = __float2bfloat16(in[j]);
    }
}

// transpose+convert all 6 MLP weights: wt[base + n*K + k] = w[k*N + n]
__global__ void conv_w_kernel(const float* __restrict__ w1a, const float* __restrict__ w1b,
                              const float* __restrict__ w2a, const float* __restrict__ w2b,
                              const float* __restrict__ w3a, const float* __restrict__ w3b,
                              bf16* __restrict__ wt) {
    int t = blockIdx.x * blockDim.x + threadIdx.x;
    const float* w; int K, N, base, r;
    if (t < 16384)       { w = w1a; K = 64;  N = 256; base = 0;      r = t; }
    else if (t < 81920)  { w = w1b; K = 256; N = 256; base = 16384;  r = t - 16384; }
    else if (t < 114688) { w = w2a; K = 256; N = 128; base = 81920;  r = t - 81920; }
    else if (t < 131072) { w = w2b; K = 128; N = 128; base = 114688; r = t - 114688; }
    else if (t < 139264) { w = w3a; K = 128; N = 64;  base = 131072; r = t - 131072; }
    else if (t < 143360) { w = w3b; K = 64;  N = 64;  base = 139264; r = t - 139264; }
    else return;
    int k = r % K, n = r / K;
    wt[base + r] = __float2bfloat16(w[(size_t)k * N + n]);
}

// edge-linear weights as packed f16 k-pairs: wef[base + p*D + col] = (w[2p][col], w[2p+1][col])
__global__ void conv_wef_kernel(const float* __restrict__ we1, const float* __restrict__ we2,
                                const float* __restrict__ we3, uint_t* __restrict__ wef) {
    int t = blockIdx.x * blockDim.x + threadIdx.x;
    const float* w; int D, base, r;
    if (t < 512)        { w = we1; D = 64;  base = 0;    r = t; }
    else if (t < 2560)  { w = we2; D = 256; base = 512;  r = t - 512; }
    else if (t < 3584)  { w = we3; D = 128; base = 2560; r = t - 2560; }
    else return;
    int p = r / D, col = r % D;
    f16x2 h = {(_Float16)w[(size_t)(2 * p) * D + col],
               (_Float16)w[(size_t)(2 * p + 1) * D + col]};
    wef[base + r] = __builtin_bit_cast(uint_t, h);
}

// ------------------------------------------------- fused message + aggregate
// t[n] = x[n] + sum_{p in [off[n],off[n+1])} relu(x[srcs[p]] + e[p] @ we + be)
// One wave per node; lane covers cols [lane*C, lane*C+C).
// 4-deep edge unroll: all gathers + scalar edge loads issued before compute.
template <int C>
__global__ __launch_bounds__(256) void msg_fused(
    const uint_t* __restrict__ each, const int* __restrict__ srcs,
    const int* __restrict__ off, const bf16* __restrict__ x,
    const uint_t* __restrict__ wef, const float* __restrict__ be,
    bf16* __restrict__ t, int N) {
    constexpr int D = C * 64;
    const int lane = threadIdx.x & 63;
    const int n = blockIdx.x * 4 + (threadIdx.x >> 6);
    if (n >= N) return;
    const int col0 = lane * C;

    uint_t wreg[8][C];
#pragma unroll
    for (int p = 0; p < 8; ++p)
#pragma unroll
        for (int c = 0; c < C; ++c) wreg[p][c] = wef[p * D + col0 + c];
    float breg[C];
#pragma unroll
    for (int c = 0; c < C; ++c) breg[c] = be[col0 + c];

    float acc[C];
#pragma unroll
    for (int c = 0; c < C; ++c) acc[c] = 0.f;

    const ushort_t* xp = (const ushort_t*)x;

    const int i0 = __builtin_amdgcn_readfirstlane(off[n]);
    const int i1 = __builtin_amdgcn_readfirstlane(off[n + 1]);

#define BF2F(u) (__builtin_bit_cast(float, (unsigned)(u) << 16))
#define H2(u) (__builtin_bit_cast(f16x2, u))

    int i = i0;
    for (; i + 4 <= i1; i += 4) {
        int s[4];
#pragma unroll
        for (int j = 0; j < 4; ++j) s[j] = __builtin_amdgcn_readfirstlane(srcs[i + j]);
        // all 4 x gathers in flight first
        ushort_t xv[4][C];
#pragma unroll
        for (int j = 0; j < 4; ++j) {
            if constexpr (C == 4) {
                *(ushort4*)xv[j] = *(const ushort4*)&xp[(size_t)s[j] * D + col0];
            } else if constexpr (C == 2) {
                *(ushort2*)xv[j] = *(const ushort2*)&xp[(size_t)s[j] * D + col0];
            } else {
                xv[j][0] = xp[(size_t)s[j] * D + col0];
            }
        }
        // all 4 wave-uniform packed edge-attr rows (scalar loads)
        uint_t e[4][8];
#pragma unroll
        for (int j = 0; j < 4; ++j)
#pragma unroll
            for (int p = 0; p < 8; ++p) e[j][p] = each[(size_t)(i + j) * 8 + p];

        float m[4][C];
#pragma unroll
        for (int j = 0; j < 4; ++j)
#pragma unroll
            for (int c = 0; c < C; ++c)
                m[j][c] = __builtin_amdgcn_fdot2(H2(e[j][0]), H2(wreg[0][c]), breg[c], false);
#pragma unroll
        for (int p = 1; p < 8; ++p)
#pragma unroll
            for (int j = 0; j < 4; ++j)
#pragma unroll
                for (int c = 0; c < C; ++c)
                    m[j][c] = __builtin_amdgcn_fdot2(H2(e[j][p]), H2(wreg[p][c]), m[j][c], false);
#pragma unroll
        for (int j = 0; j < 4; ++j)
#pragma unroll
            for (int c = 0; c < C; ++c)
                acc[c] += fmaxf(m[j][c] + BF2F(xv[j][c]), 0.f);
    }
    for (; i < i1; ++i) {
        const int s0 = __builtin_amdgcn_readfirstlane(srcs[i]);
        ushort_t xv0[C];
        if constexpr (C == 4) {
            *(ushort4*)xv0 = *(const ushort4*)&xp[(size_t)s0 * D + col0];
        } else if constexpr (C == 2) {
            *(ushort2*)xv0 = *(const ushort2*)&xp[(size_t)s0 * D + col0];
        } else {
            xv0[0] = xp[(size_t)s0 * D + col0];
        }
        uint_t e0[8];
#pragma unroll
        for (int p = 0; p < 8; ++p) e0[p] = each[(size_t)i * 8 + p];
        float m0[C];
#pragma unroll
        for (int c = 0; c < C; ++c)
            m0[c] = __builtin_amdgcn_fdot2(H2(e0[0]), H2(wreg[0][c]), breg[c], false);
#pragma unroll
        for (int p = 1; p < 8; ++p)
#pragma unroll
            for (int c = 0; c < C; ++c)
                m0[c] = __builtin_amdgcn_fdot2(H2(e0[p]), H2(wreg[p][c]), m0[c], false);
#pragma unroll
        for (int c = 0; c < C; ++c) acc[c] += fmaxf(m0[c] + BF2F(xv0[c]), 0.f);
    }

#pragma unroll
    for (int c = 0; c < C; ++c) {
        float xo = BF2F(xp[(size_t)n * D + col0 + c]);
        t[(size_t)n * D + col0 + c] = __float2bfloat16(xo + acc[c]);
    }
#undef BF2F
#undef H2
}

// --------------------------------------------------------- bf16 MFMA GEMM
// mode 1: relu  mode 2: bn(relu)  mode 3: bn(relu) + atomic pool (no C write)
template <int NCOLS>
__global__ __launch_bounds__(256) void gemm_mfma(
    const bf16* __restrict__ A, const bf16* __restrict__ Wt,
    const float* __restrict__ bias, const float* __restrict__ bng,
    const float* __restrict__ bnb, const float* __restrict__ bnm,
    const float* __restrict__ bnv, bf16* __restrict__ C,
    const int* __restrict__ batch, float* __restrict__ pooled,
    int M, int K, int mode) {
    constexpr int NT = NCOLS / 16;
    const int lane = threadIdx.x & 63;
    const int w = threadIdx.x >> 6;
    const int mbase = blockIdx.x * 128 + w * 32;
    const int r16 = lane & 15;
    const int kg = lane >> 4;

    f32x4 acc[2][NT];
#pragma unroll
    for (int f = 0; f < 2; ++f)
#pragma unroll
        for (int nt = 0; nt < NT; ++nt) acc[f][nt] = (f32x4){0.f, 0.f, 0.f, 0.f};

    const short* Ap = (const short*)A;
    const short* Wp = (const short*)Wt;

    for (int k0 = 0; k0 < K; k0 += 32) {
        short8v a0 = *(const short8v*)&Ap[(size_t)(mbase + r16) * K + k0 + kg * 8];
        short8v a1 = *(const short8v*)&Ap[(size_t)(mbase + 16 + r16) * K + k0 + kg * 8];
#pragma unroll
        for (int nt = 0; nt < NT; ++nt) {
            short8v b = *(const short8v*)&Wp[(size_t)(nt * 16 + r16) * K + k0 + kg * 8];
            acc[0][nt] = __builtin_amdgcn_mfma_f32_16x16x32_bf16(a0, b, acc[0][nt], 0, 0, 0);
            acc[1][nt] = __builtin_amdgcn_mfma_f32_16x16x32_bf16(a1, b, acc[1][nt], 0, 0, 0);
        }
    }

    float bs[NT], sc[NT], sh[NT];
#pragma unroll
    for (int nt = 0; nt < NT; ++nt) {
        int col = nt * 16 + r16;
        bs[nt] = bias[col];
        sc[nt] = 1.f; sh[nt] = 0.f;
        if (mode >= 2) {
            sc[nt] = rsqrtf(bnv[col] + BN_EPS) * bng[col];
            sh[nt] = bnb[col] - bnm[col] * sc[nt];
        }
    }

#pragma unroll
    for (int f = 0; f < 2; ++f) {
#pragma unroll
        for (int rg = 0; rg < 4; ++rg) {
            int row = mbase + f * 16 + kg * 4 + rg;
            if (row >= M) continue;
            int g = 0;
            if (mode == 3) g = min(max(batch[row], 0), 127);
#pragma unroll
            for (int nt = 0; nt < NT; ++nt) {
                int col = nt * 16 + r16;
                float z = acc[f][nt][rg] + bs[nt];
                z = fmaxf(z, 0.f);
                if (mode >= 2) z = z * sc[nt] + sh[nt];
                if (mode == 3)
                    atomicAdd(&pooled[g * NCOLS + col], z);
                else
                    C[(size_t)row * NCOLS + col] = __float2bfloat16(z);
            }
        }
    }
}

// -------------------------------------------------------------------- head
__global__ __launch_bounds__(128) void head_kernel(
    const float* __restrict__ pooled, const float* __restrict__ w1,
    const float* __restrict__ b1, const float* __restrict__ w2,
    const float* __restrict__ b2, float* __restrict__ out) {
    const int g = threadIdx.x;
    float p[64];
#pragma unroll
    for (int i = 0; i < 64; ++i) p[i] = pooled[g * 64 + i];
    float o = b2[0];
#pragma unroll
    for (int j = 0; j < 16; ++j) {
        float hsum = b1[j];
#pragma unroll
        for (int i = 0; i < 64; ++i) hsum = fmaf(p[i], w1[i * 16 + j], hsum);
        o = fmaf(fmaxf(hsum, 0.f), w2[j], o);
    }
    out[g] = o;
}

// ------------------------------------------------------------------ launch
extern "C" void kernel_launch(void* const* d_in, const int* in_sizes, int n_in,
                              void* d_out, int out_size, void* d_ws,
                              size_t ws_size, hipStream_t stream) {
    const float* x     = (const float*)d_in[0];
    const float* ea    = (const float*)d_in[1];
    const int*   ei    = (const int*)d_in[2];
    const int*   batch = (const int*)d_in[3];
    const float* we1 = (const float*)d_in[4];
    const float* be1 = (const float*)d_in[5];
    const float* w1a = (const float*)d_in[6];
    const float* b1a = (const float*)d_in[7];
    const float* w1b = (const float*)d_in[8];
    const float* b1b = (const float*)d_in[9];
    const float* bn1g = (const float*)d_in[10];
    const float* bn1b = (const float*)d_in[11];
    const float* bn1m = (const float*)d_in[12];
    const float* bn1v = (const float*)d_in[13];
    const float* we2 = (const float*)d_in[14];
    const float* be2 = (const float*)d_in[15];
    const float* w2a = (const float*)d_in[16];
    const float* b2a = (const float*)d_in[17];
    const float* w2b = (const float*)d_in[18];
    const float* b2b = (const float*)d_in[19];
    const float* bn2g = (const float*)d_in[20];
    const float* bn2b = (const float*)d_in[21];
    const float* bn2m = (const float*)d_in[22];
    const float* bn2v = (const float*)d_in[23];
    const float* we3 = (const float*)d_in[24];
    const float* be3 = (const float*)d_in[25];
    const float* w3a = (const float*)d_in[26];
    const float* b3a = (const float*)d_in[27];
    const float* w3b = (const float*)d_in[28];
    const float* b3b = (const float*)d_in[29];
    const float* bn3g = (const float*)d_in[30];
    const float* bn3b = (const float*)d_in[31];
    const float* bn3m = (const float*)d_in[32];
    const float* bn3v = (const float*)d_in[33];
    const float* fc1w = (const float*)d_in[34];
    const float* fc1b = (const float*)d_in[35];
    const float* fc2w = (const float*)d_in[36];
    const float* fc2b = (const float*)d_in[37];

    const int N = in_sizes[0] / 64;
    const int E = in_sizes[1] / 16;
    const int M_pad = ((N + 127) / 128) * 128;
    const int* src = ei;
    const int* dst = ei + E;

    char* wsp = (char*)d_ws;
    auto alloc = [&](size_t bytes) -> void* {
        void* p = (void*)wsp;
        wsp += (bytes + 255) & ~(size_t)255;
        return p;
    };
    const int nb = (N + 255) / 256;
    int* deg    = (int*)alloc((size_t)N * 4);
    int* off    = (int*)alloc((size_t)(N + 1) * 4);
    int* cur    = (int*)alloc((size_t)N * 4);
    int* bsum   = (int*)alloc((size_t)nb * 4);
    int* srcs   = (int*)alloc((size_t)E * 4);
    uint_t* each = (uint_t*)alloc((size_t)E * 8 * 4);
    bf16* xb    = (bf16*)alloc((size_t)N * 64 * 2);
    bf16* tb    = (bf16*)alloc((size_t)M_pad * 256 * 2);
    bf16* ub    = (bf16*)alloc((size_t)M_pad * 256 * 2);
    bf16* hb    = (bf16*)alloc((size_t)M_pad * 256 * 2);
    bf16* wt    = (bf16*)alloc((size_t)143360 * 2);
    uint_t* wef = (uint_t*)alloc((size_t)3584 * 4);
    float* pooled = (float*)alloc(128 * 64 * 4);

    bf16* wt1a = wt + 0;
    bf16* wt1b = wt + 16384;
    bf16* wt2a = wt + 81920;
    bf16* wt2b = wt + 114688;
    bf16* wt3a = wt + 131072;
    bf16* wt3b = wt + 139264;
    uint_t* wef1 = wef + 0;
    uint_t* wef2 = wef + 512;
    uint_t* wef3 = wef + 2560;

    hipMemsetAsync(deg, 0, (size_t)N * 4, stream);
    hipMemsetAsync(pooled, 0, 128 * 64 * 4, stream);

    conv_bf16_kernel<<<(N * 64 / 4 + 255) / 256, 256, 0, stream>>>(x, xb, N * 64);
    conv_w_kernel<<<(143360 + 255) / 256, 256, 0, stream>>>(w1a, w1b, w2a, w2b,
                                                            w3a, w3b, wt);
    conv_wef_kernel<<<(3584 + 255) / 256, 256, 0, stream>>>(we1, we2, we3, wef);

    int eb = (E + 255) / 256;
    count_kernel<<<eb, 256, 0, stream>>>(dst, deg, E, N);
    scan1_kernel<<<nb, 256, 0, stream>>>(deg, bsum, N);
    scan2_kernel<<<1, 256, 0, stream>>>(bsum, nb);
    scan3_kernel<<<nb, 256, 0, stream>>>(deg, bsum, off, cur, N);
    fill_kernel<<<eb, 256, 0, stream>>>(src, dst, ea, cur, srcs, each, E, N);

    const int gblk = M_pad / 128;
    const int mblk = (N + 3) / 4;

    // ---- layer 1 (64 -> 256)
    msg_fused<1><<<mblk, 256, 0, stream>>>(each, srcs, off, xb, wef1, be1, tb, N);
    gemm_mfma<256><<<gblk, 256, 0, stream>>>(tb, wt1a, b1a, nullptr, nullptr, nullptr,
                                             nullptr, ub, nullptr, nullptr, N, 64, 1);
    gemm_mfma<256><<<gblk, 256, 0, stream>>>(ub, wt1b, b1b, bn1g, bn1b, bn1m, bn1v,
                                             hb, nullptr, nullptr, N, 256, 2);
    // ---- layer 2 (256 -> 128)
    msg_fused<4><<<mblk, 256, 0, stream>>>(each, srcs, off, hb, wef2, be2, tb, N);
    gemm_mfma<128><<<gblk, 256, 0, stream>>>(tb, wt2a, b2a, nullptr, nullptr, nullptr,
                                             nullptr, ub, nullptr, nullptr, N, 256, 1);
    gemm_mfma<128><<<gblk, 256, 0, stream>>>(ub, wt2b, b2b, bn2g, bn2b, bn2m, bn2v,
                                             hb, nullptr, nullptr, N, 128, 2);
    // ---- layer 3 (128 -> 64)
    msg_fused<2><<<mblk, 256, 0, stream>>>(each, srcs, off, hb, wef3, be3, tb, N);
    gemm_mfma<64><<<gblk, 256, 0, stream>>>(tb, wt3a, b3a, nullptr, nullptr, nullptr,
                                            nullptr, ub, nullptr, nullptr, N, 128, 1);
    // final GEMM: bn(relu) + fused pooling via atomics, no hb write
    gemm_mfma<64><<<gblk, 256, 0, stream>>>(ub, wt3b, b3b, bn3g, bn3b, bn3m, bn3v,
                                            nullptr, batch, pooled, N, 64, 3);

    // ---- head
    head_kernel<<<1, 128, 0, stream>>>(pooled, fc1w, fc1b, fc2w, fc2b, (float*)d_out);
}

// Round 7
// 445.529 us; speedup vs baseline: 2.8458x; 1.1016x over previous
//
#include <hip/hip_runtime.h>
#include <hip/hip_bf16.h>

#define BN_EPS 1e-5f

typedef __attribute__((ext_vector_type(8))) short short8v;
typedef __attribute__((ext_vector_type(4))) float f32x4;
typedef _Float16 f16x2 __attribute__((ext_vector_type(2)));
typedef __hip_bfloat16 bf16;
typedef unsigned short ushort_t;
typedef unsigned int uint_t;

// ---------------------------------------------------------------- CSR build
__global__ void count_kernel(const int* __restrict__ dst, int* __restrict__ deg,
                             int E, int N) {
    int i = blockIdx.x * blockDim.x + threadIdx.x;
    if (i >= E) return;
    int d = dst[i];
    d = min(max(d, 0), N - 1);
    atomicAdd(&deg[d], 1);
}

// pass 1 — per-block sums (256 elems/block)
__global__ __launch_bounds__(256) void scan1_kernel(const int* __restrict__ deg,
                                                    int* __restrict__ bsum, int N) {
    int t = threadIdx.x, b = blockIdx.x;
    int i = b * 256 + t;
    int v = (i < N) ? deg[i] : 0;
#pragma unroll
    for (int d = 32; d; d >>= 1) v += __shfl_xor(v, d, 64);
    __shared__ int ws[4];
    if ((t & 63) == 0) ws[t >> 6] = v;
    __syncthreads();
    if (t == 0) bsum[b] = ws[0] + ws[1] + ws[2] + ws[3];
}

// pass 2 — per-block scan; block base computed internally from bsum[0..b)
__global__ __launch_bounds__(256) void scan3_kernel(const int* __restrict__ deg,
                                                    const int* __restrict__ bsum,
                                                    int* __restrict__ off,
                                                    int* __restrict__ cur,
                                                    int N, int nb) {
    int t = threadIdx.x, b = blockIdx.x;
    int lane = t & 63, w = t >> 6;

    // base = sum of bsum[0..b)
    int partial = 0;
    for (int j = t; j < b; j += 256) partial += bsum[j];
#pragma unroll
    for (int d = 32; d; d >>= 1) partial += __shfl_xor(partial, d, 64);
    __shared__ int bsm[4];
    if (lane == 0) bsm[w] = partial;
    __syncthreads();
    int base = bsm[0] + bsm[1] + bsm[2] + bsm[3];

    int i = b * 256 + t;
    int v = (i < N) ? deg[i] : 0;
    int inc = v;
#pragma unroll
    for (int d = 1; d < 64; d <<= 1) {
        int u = __shfl_up(inc, d, 64);
        if (lane >= d) inc += u;
    }
    __shared__ int ws[4];
    if (lane == 63) ws[w] = inc;
    __syncthreads();
    for (int j = 0; j < w; ++j) base += ws[j];
    int excl = base + inc - v;
    if (i < N) { off[i] = excl; cur[i] = excl; }
    if (i == N - 1) off[N] = excl + v;
}

// fill: CSR edge placement; emits permuted src ids AND permuted edge_attr
// packed as 8 x (2 x f16) per edge
__global__ void fill_kernel(const int* __restrict__ src, const int* __restrict__ dst,
                            const float* __restrict__ ea, int* __restrict__ cur,
                            int* __restrict__ srcs, uint_t* __restrict__ each,
                            int E, int N) {
    int i = blockIdx.x * blockDim.x + threadIdx.x;
    if (i >= E) return;
    int d = dst[i];
    d = min(max(d, 0), N - 1);
    int p = atomicAdd(&cur[d], 1);
    srcs[p] = min(max(src[i], 0), N - 1);
    uint_t pk[8];
#pragma unroll
    for (int q = 0; q < 4; ++q) {
        float4 a = *(const float4*)&ea[(size_t)i * 16 + q * 4];
        f16x2 h0 = {(_Float16)a.x, (_Float16)a.y};
        f16x2 h1 = {(_Float16)a.z, (_Float16)a.w};
        pk[q * 2 + 0] = __builtin_bit_cast(uint_t, h0);
        pk[q * 2 + 1] = __builtin_bit_cast(uint_t, h1);
    }
    *(uint4*)&each[(size_t)p * 8 + 0] = *(uint4*)&pk[0];
    *(uint4*)&each[(size_t)p * 8 + 4] = *(uint4*)&pk[4];
}

// ------------------------------------------- mega convert + zero kernel
// seg0: x -> bf16 (4/thread)   seg1: 6 MLP weights transposed -> bf16
// seg2: edge weights -> packed f16 pairs   seg3: zero deg   seg4: zero pooled
__global__ void megaconv_kernel(
    const float* __restrict__ x, bf16* __restrict__ xb, int nx4,
    const float* __restrict__ w1a, const float* __restrict__ w1b,
    const float* __restrict__ w2a, const float* __restrict__ w2b,
    const float* __restrict__ w3a, const float* __restrict__ w3b,
    bf16* __restrict__ wt,
    const float* __restrict__ we1, const float* __restrict__ we2,
    const float* __restrict__ we3, uint_t* __restrict__ wef,
    int* __restrict__ deg, int N, float* __restrict__ pooled) {
    int t = blockIdx.x * blockDim.x + threadIdx.x;
    if (t < nx4) {
        int i = t * 4;
        float4 v = *(const float4*)&x[i];
        xb[i + 0] = __float2bfloat16(v.x);
        xb[i + 1] = __float2bfloat16(v.y);
        xb[i + 2] = __float2bfloat16(v.z);
        xb[i + 3] = __float2bfloat16(v.w);
        return;
    }
    t -= nx4;
    if (t < 143360) {
        const float* w; int K, Nc, base, r;
        if (t < 16384)       { w = w1a; K = 64;  Nc = 256; base = 0;      r = t; }
        else if (t < 81920)  { w = w1b; K = 256; Nc = 256; base = 16384;  r = t - 16384; }
        else if (t < 114688) { w = w2a; K = 256; Nc = 128; base = 81920;  r = t - 81920; }
        else if (t < 131072) { w = w2b; K = 128; Nc = 128; base = 114688; r = t - 114688; }
        else if (t < 139264) { w = w3a; K = 128; Nc = 64;  base = 131072; r = t - 131072; }
        else                 { w = w3b; K = 64;  Nc = 64;  base = 139264; r = t - 139264; }
        int k = r % K, n = r / K;
        wt[base + r] = __float2bfloat16(w[(size_t)k * Nc + n]);
        return;
    }
    t -= 143360;
    if (t < 3584) {
        const float* w; int D, base, r;
        if (t < 512)        { w = we1; D = 64;  base = 0;    r = t; }
        else if (t < 2560)  { w = we2; D = 256; base = 512;  r = t - 512; }
        else                { w = we3; D = 128; base = 2560; r = t - 2560; }
        int p = r / D, col = r % D;
        f16x2 h = {(_Float16)w[(size_t)(2 * p) * D + col],
                   (_Float16)w[(size_t)(2 * p + 1) * D + col]};
        wef[base + r] = __builtin_bit_cast(uint_t, h);
        return;
    }
    t -= 3584;
    {
        int nd4 = (N + 3) / 4;
        if (t < nd4) {
            int i = t * 4;
#pragma unroll
            for (int j = 0; j < 4; ++j)
                if (i + j < N) deg[i + j] = 0;
            return;
        }
        t -= nd4;
        if (t < 2048) {
            *(float4*)&pooled[t * 4] = make_float4(0.f, 0.f, 0.f, 0.f);
        }
    }
}

// ------------------------------------------------- fused message + aggregate
// t[n] = x[n] + sum_{p in [off[n],off[n+1])} relu(x[srcs[p]] + e[p] @ we + be)
// One wave per node; lane covers cols [lane*C, lane*C+C).
// srcs software-pipelined: next group's indices prefetched before compute.
template <int C>
__global__ __launch_bounds__(256) void msg_fused(
    const uint_t* __restrict__ each, const int* __restrict__ srcs,
    const int* __restrict__ off, const bf16* __restrict__ x,
    const uint_t* __restrict__ wef, const float* __restrict__ be,
    bf16* __restrict__ t, int N) {
    constexpr int D = C * 64;
    const int lane = threadIdx.x & 63;
    const int n = blockIdx.x * 4 + (threadIdx.x >> 6);
    if (n >= N) return;
    const int col0 = lane * C;

    uint_t wreg[8][C];
#pragma unroll
    for (int p = 0; p < 8; ++p)
#pragma unroll
        for (int c = 0; c < C; ++c) wreg[p][c] = wef[p * D + col0 + c];
    float breg[C];
#pragma unroll
    for (int c = 0; c < C; ++c) breg[c] = be[col0 + c];

    float acc[C];
#pragma unroll
    for (int c = 0; c < C; ++c) acc[c] = 0.f;

    const ushort_t* xp = (const ushort_t*)x;

    const int i0 = __builtin_amdgcn_readfirstlane(off[n]);
    const int i1 = __builtin_amdgcn_readfirstlane(off[n + 1]);

#define BF2F(u) (__builtin_bit_cast(float, (unsigned)(u) << 16))
#define H2(u) (__builtin_bit_cast(f16x2, u))

    int i = i0;
    int sN[4] = {0, 0, 0, 0};
    if (i + 4 <= i1) {
#pragma unroll
        for (int j = 0; j < 4; ++j)
            sN[j] = __builtin_amdgcn_readfirstlane(srcs[i + j]);
    }
    for (; i + 4 <= i1; i += 4) {
        int s[4];
#pragma unroll
        for (int j = 0; j < 4; ++j) s[j] = sN[j];
        // all 4 x gathers in flight first (indices ready from prev iter)
        ushort_t xv[4][C];
#pragma unroll
        for (int j = 0; j < 4; ++j) {
            if constexpr (C == 4) {
                *(ushort4*)xv[j] = *(const ushort4*)&xp[(size_t)s[j] * D + col0];
            } else if constexpr (C == 2) {
                *(ushort2*)xv[j] = *(const ushort2*)&xp[(size_t)s[j] * D + col0];
            } else {
                xv[j][0] = xp[(size_t)s[j] * D + col0];
            }
        }
        // prefetch next group's indices
        if (i + 8 <= i1) {
#pragma unroll
            for (int j = 0; j < 4; ++j)
                sN[j] = __builtin_amdgcn_readfirstlane(srcs[i + 4 + j]);
        }
        // wave-uniform packed edge-attr rows (scalar loads)
        uint_t e[4][8];
#pragma unroll
        for (int j = 0; j < 4; ++j)
#pragma unroll
            for (int p = 0; p < 8; ++p) e[j][p] = each[(size_t)(i + j) * 8 + p];

        float m[4][C];
#pragma unroll
        for (int j = 0; j < 4; ++j)
#pragma unroll
            for (int c = 0; c < C; ++c)
                m[j][c] = __builtin_amdgcn_fdot2(H2(e[j][0]), H2(wreg[0][c]), breg[c], false);
#pragma unroll
        for (int p = 1; p < 8; ++p)
#pragma unroll
            for (int j = 0; j < 4; ++j)
#pragma unroll
                for (int c = 0; c < C; ++c)
                    m[j][c] = __builtin_amdgcn_fdot2(H2(e[j][p]), H2(wreg[p][c]), m[j][c], false);
#pragma unroll
        for (int j = 0; j < 4; ++j)
#pragma unroll
            for (int c = 0; c < C; ++c)
                acc[c] += fmaxf(m[j][c] + BF2F(xv[j][c]), 0.f);
    }
    for (; i < i1; ++i) {
        const int s0 = __builtin_amdgcn_readfirstlane(srcs[i]);
        ushort_t xv0[C];
        if constexpr (C == 4) {
            *(ushort4*)xv0 = *(const ushort4*)&xp[(size_t)s0 * D + col0];
        } else if constexpr (C == 2) {
            *(ushort2*)xv0 = *(const ushort2*)&xp[(size_t)s0 * D + col0];
        } else {
            xv0[0] = xp[(size_t)s0 * D + col0];
        }
        uint_t e0[8];
#pragma unroll
        for (int p = 0; p < 8; ++p) e0[p] = each[(size_t)i * 8 + p];
        float m0[C];
#pragma unroll
        for (int c = 0; c < C; ++c)
            m0[c] = __builtin_amdgcn_fdot2(H2(e0[0]), H2(wreg[0][c]), breg[c], false);
#pragma unroll
        for (int p = 1; p < 8; ++p)
#pragma unroll
            for (int c = 0; c < C; ++c)
                m0[c] = __builtin_amdgcn_fdot2(H2(e0[p]), H2(wreg[p][c]), m0[c], false);
#pragma unroll
        for (int c = 0; c < C; ++c) acc[c] += fmaxf(m0[c] + BF2F(xv0[c]), 0.f);
    }

#pragma unroll
    for (int c = 0; c < C; ++c) {
        float xo = BF2F(xp[(size_t)n * D + col0 + c]);
        t[(size_t)n * D + col0 + c] = __float2bfloat16(xo + acc[c]);
    }
#undef BF2F
#undef H2
}

// --------------------------------------------------------- fused 2-GEMM MLP
// out = epi( relu(A @ W1 + b1) @ W2 + b2 )
// u staged in LDS as bf16 (row-major, +8 half pad -> 16B-aligned rows).
// mode 2: bn(relu) -> C    mode 3: bn(relu) + atomic pool (no C write)
template <int H, int NC>
__global__ __launch_bounds__(256) void mlp_fused(
    const bf16* __restrict__ A, const bf16* __restrict__ W1t,
    const float* __restrict__ b1, const bf16* __restrict__ W2t,
    const float* __restrict__ b2, const float* __restrict__ bng,
    const float* __restrict__ bnb, const float* __restrict__ bnm,
    const float* __restrict__ bnv, bf16* __restrict__ C,
    const int* __restrict__ batch, float* __restrict__ pooled,
    int M, int K1, int mode) {
    constexpr int NT1 = H / 16;
    constexpr int NT2 = NC / 16;
    constexpr int LDH = H + 8;
    __shared__ __align__(16) ushort_t u_lds[128 * LDH];

    const int lane = threadIdx.x & 63;
    const int w = threadIdx.x >> 6;
    const int r16 = lane & 15;
    const int kg = lane >> 4;
    const int mbase = blockIdx.x * 128 + w * 32;
    const int lbase = w * 32;

    const short* Ap = (const short*)A;
    const short* W1p = (const short*)W1t;
    const short* W2p = (const short*)W2t;

    // ---- stage 1: u = relu(A @ W1 + b1) -> LDS (bf16)
    {
        f32x4 acc[2][NT1];
#pragma unroll
        for (int f = 0; f < 2; ++f)
#pragma unroll
            for (int nt = 0; nt < NT1; ++nt) acc[f][nt] = (f32x4){0.f, 0.f, 0.f, 0.f};

        for (int k0 = 0; k0 < K1; k0 += 32) {
            short8v a0 = *(const short8v*)&Ap[(size_t)(mbase + r16) * K1 + k0 + kg * 8];
            short8v a1 = *(const short8v*)&Ap[(size_t)(mbase + 16 + r16) * K1 + k0 + kg * 8];
#pragma unroll
            for (int nt = 0; nt < NT1; ++nt) {
                short8v b = *(const short8v*)&W1p[(size_t)(nt * 16 + r16) * K1 + k0 + kg * 8];
                acc[0][nt] = __builtin_amdgcn_mfma_f32_16x16x32_bf16(a0, b, acc[0][nt], 0, 0, 0);
                acc[1][nt] = __builtin_amdgcn_mfma_f32_16x16x32_bf16(a1, b, acc[1][nt], 0, 0, 0);
            }
        }
#pragma unroll
        for (int nt = 0; nt < NT1; ++nt) {
            int col = nt * 16 + r16;
            float bs = b1[col];
#pragma unroll
            for (int f = 0; f < 2; ++f) {
#pragma unroll
                for (int rg = 0; rg < 4; ++rg) {
                    int rl = lbase + f * 16 + kg * 4 + rg;
                    float z = fmaxf(acc[f][nt][rg] + bs, 0.f);
                    u_lds[rl * LDH + col] =
                        __builtin_bit_cast(ushort_t, __float2bfloat16(z));
                }
            }
        }
    }
    __syncthreads();

    // ---- stage 2: out = epi(u @ W2 + b2)
    f32x4 acc2[2][NT2];
#pragma unroll
    for (int f = 0; f < 2; ++f)
#pragma unroll
        for (int nt = 0; nt < NT2; ++nt) acc2[f][nt] = (f32x4){0.f, 0.f, 0.f, 0.f};

    for (int k0 = 0; k0 < H; k0 += 32) {
        short8v a0 = *(const short8v*)&u_lds[(lbase + r16) * LDH + k0 + kg * 8];
        short8v a1 = *(const short8v*)&u_lds[(lbase + 16 + r16) * LDH + k0 + kg * 8];
#pragma unroll
        for (int nt = 0; nt < NT2; ++nt) {
            short8v b = *(const short8v*)&W2p[(size_t)(nt * 16 + r16) * H + k0 + kg * 8];
            acc2[0][nt] = __builtin_amdgcn_mfma_f32_16x16x32_bf16(a0, b, acc2[0][nt], 0, 0, 0);
            acc2[1][nt] = __builtin_amdgcn_mfma_f32_16x16x32_bf16(a1, b, acc2[1][nt], 0, 0, 0);
        }
    }

    float bs[NT2], sc[NT2], sh[NT2];
#pragma unroll
    for (int nt = 0; nt < NT2; ++nt) {
        int col = nt * 16 + r16;
        bs[nt] = b2[col];
        sc[nt] = rsqrtf(bnv[col] + BN_EPS) * bng[col];
        sh[nt] = bnb[col] - bnm[col] * sc[nt];
    }

#pragma unroll
    for (int f = 0; f < 2; ++f) {
#pragma unroll
        for (int rg = 0; rg < 4; ++rg) {
            int row = mbase + f * 16 + kg * 4 + rg;
            if (row >= M) continue;
            int g = 0;
            if (mode == 3) g = min(max(batch[row], 0), 127);
#pragma unroll
            for (int nt = 0; nt < NT2; ++nt) {
                int col = nt * 16 + r16;
                float z = fmaxf(acc2[f][nt][rg] + bs[nt], 0.f);
                z = z * sc[nt] + sh[nt];
                if (mode == 3)
                    atomicAdd(&pooled[g * NC + col], z);
                else
                    C[(size_t)row * NC + col] = __float2bfloat16(z);
            }
        }
    }
}

// -------------------------------------------------------------------- head
__global__ __launch_bounds__(128) void head_kernel(
    const float* __restrict__ pooled, const float* __restrict__ w1,
    const float* __restrict__ b1, const float* __restrict__ w2,
    const float* __restrict__ b2, float* __restrict__ out) {
    const int g = threadIdx.x;
    float p[64];
#pragma unroll
    for (int i = 0; i < 64; ++i) p[i] = pooled[g * 64 + i];
    float o = b2[0];
#pragma unroll
    for (int j = 0; j < 16; ++j) {
        float hsum = b1[j];
#pragma unroll
        for (int i = 0; i < 64; ++i) hsum = fmaf(p[i], w1[i * 16 + j], hsum);
        o = fmaf(fmaxf(hsum, 0.f), w2[j], o);
    }
    out[g] = o;
}

// ------------------------------------------------------------------ launch
extern "C" void kernel_launch(void* const* d_in, const int* in_sizes, int n_in,
                              void* d_out, int out_size, void* d_ws,
                              size_t ws_size, hipStream_t stream) {
    const float* x     = (const float*)d_in[0];
    const float* ea    = (const float*)d_in[1];
    const int*   ei    = (const int*)d_in[2];
    const int*   batch = (const int*)d_in[3];
    const float* we1 = (const float*)d_in[4];
    const float* be1 = (const float*)d_in[5];
    const float* w1a = (const float*)d_in[6];
    const float* b1a = (const float*)d_in[7];
    const float* w1b = (const float*)d_in[8];
    const float* b1b = (const float*)d_in[9];
    const float* bn1g = (const float*)d_in[10];
    const float* bn1b = (const float*)d_in[11];
    const float* bn1m = (const float*)d_in[12];
    const float* bn1v = (const float*)d_in[13];
    const float* we2 = (const float*)d_in[14];
    const float* be2 = (const float*)d_in[15];
    const float* w2a = (const float*)d_in[16];
    const float* b2a = (const float*)d_in[17];
    const float* w2b = (const float*)d_in[18];
    const float* b2b = (const float*)d_in[19];
    const float* bn2g = (const float*)d_in[20];
    const float* bn2b = (const float*)d_in[21];
    const float* bn2m = (const float*)d_in[22];
    const float* bn2v = (const float*)d_in[23];
    const float* we3 = (const float*)d_in[24];
    const float* be3 = (const float*)d_in[25];
    const float* w3a = (const float*)d_in[26];
    const float* b3a = (const float*)d_in[27];
    const float* w3b = (const float*)d_in[28];
    const float* b3b = (const float*)d_in[29];
    const float* bn3g = (const float*)d_in[30];
    const float* bn3b = (const float*)d_in[31];
    const float* bn3m = (const float*)d_in[32];
    const float* bn3v = (const float*)d_in[33];
    const float* fc1w = (const float*)d_in[34];
    const float* fc1b = (const float*)d_in[35];
    const float* fc2w = (const float*)d_in[36];
    const float* fc2b = (const float*)d_in[37];

    const int N = in_sizes[0] / 64;
    const int E = in_sizes[1] / 16;
    const int M_pad = ((N + 127) / 128) * 128;
    const int* src = ei;
    const int* dst = ei + E;

    char* wsp = (char*)d_ws;
    auto alloc = [&](size_t bytes) -> void* {
        void* p = (void*)wsp;
        wsp += (bytes + 255) & ~(size_t)255;
        return p;
    };
    const int nb = (N + 255) / 256;
    int* deg    = (int*)alloc((size_t)N * 4);
    int* off    = (int*)alloc((size_t)(N + 1) * 4);
    int* cur    = (int*)alloc((size_t)N * 4);
    int* bsum   = (int*)alloc((size_t)nb * 4);
    int* srcs   = (int*)alloc((size_t)E * 4);
    uint_t* each = (uint_t*)alloc((size_t)E * 8 * 4);
    bf16* xb    = (bf16*)alloc((size_t)N * 64 * 2);
    bf16* tb    = (bf16*)alloc((size_t)M_pad * 256 * 2);
    bf16* hb    = (bf16*)alloc((size_t)M_pad * 256 * 2);
    bf16* wt    = (bf16*)alloc((size_t)143360 * 2);
    uint_t* wef = (uint_t*)alloc((size_t)3584 * 4);
    float* pooled = (float*)alloc(128 * 64 * 4);

    bf16* wt1a = wt + 0;
    bf16* wt1b = wt + 16384;
    bf16* wt2a = wt + 81920;
    bf16* wt2b = wt + 114688;
    bf16* wt3a = wt + 131072;
    bf16* wt3b = wt + 139264;
    uint_t* wef1 = wef + 0;
    uint_t* wef2 = wef + 512;
    uint_t* wef3 = wef + 2560;

    // mega convert + zero (replaces 3 convs + 2 memsets)
    {
        int nx4 = N * 64 / 4;
        int total = nx4 + 143360 + 3584 + (N + 3) / 4 + 2048;
        megaconv_kernel<<<(total + 255) / 256, 256, 0, stream>>>(
            x, xb, nx4, w1a, w1b, w2a, w2b, w3a, w3b, wt, we1, we2, we3, wef,
            deg, N, pooled);
    }

    int eb = (E + 255) / 256;
    count_kernel<<<eb, 256, 0, stream>>>(dst, deg, E, N);
    scan1_kernel<<<nb, 256, 0, stream>>>(deg, bsum, N);
    scan3_kernel<<<nb, 256, 0, stream>>>(deg, bsum, off, cur, N, nb);
    fill_kernel<<<eb, 256, 0, stream>>>(src, dst, ea, cur, srcs, each, E, N);

    const int gblk = M_pad / 128;
    const int mblk = (N + 3) / 4;

    // ---- layer 1 (64 -> 256 -> 256)
    msg_fused<1><<<mblk, 256, 0, stream>>>(each, srcs, off, xb, wef1, be1, tb, N);
    mlp_fused<256, 256><<<gblk, 256, 0, stream>>>(tb, wt1a, b1a, wt1b, b1b,
                                                  bn1g, bn1b, bn1m, bn1v,
                                                  hb, nullptr, nullptr, N, 64, 2);
    // ---- layer 2 (256 -> 128 -> 128)
    msg_fused<4><<<mblk, 256, 0, stream>>>(each, srcs, off, hb, wef2, be2, tb, N);
    mlp_fused<128, 128><<<gblk, 256, 0, stream>>>(tb, wt2a, b2a, wt2b, b2b,
                                                  bn2g, bn2b, bn2m, bn2v,
                                                  hb, nullptr, nullptr, N, 256, 2);
    // ---- layer 3 (128 -> 64 -> 64) + fused pooling
    msg_fused<2><<<mblk, 256, 0, stream>>>(each, srcs, off, hb, wef3, be3, tb, N);
    mlp_fused<64, 64><<<gblk, 256, 0, stream>>>(tb, wt3a, b3a, wt3b, b3b,
                                                bn3g, bn3b, bn3m, bn3v,
                                                nullptr, batch, pooled, N, 128, 3);

    // ---- head
    head_kernel<<<1, 128, 0, stream>>>(pooled, fc1w, fc1b, fc2w, fc2b, (float*)d_out);
}